// Round 5
// baseline (471.038 us; speedup 1.0000x reference)
//
#include <hip/hip_runtime.h>
#include <stdint.h>

#define DEV __device__ __forceinline__

typedef __bf16 bf16x8 __attribute__((ext_vector_type(8)));
typedef unsigned short u16x8 __attribute__((ext_vector_type(8)));
typedef float f32x4 __attribute__((ext_vector_type(4)));

// n-dimension padded stride: 992 = 31*32 -> NS*2 bytes ≡ 0 mod 64 (aligned
// epilogue segments, no partial-line write-allocate), and 64*NS/128 = 496
// m-tiles divisible by 8 (full XCD swizzle grid, exact reduce chunks).
#define NS 992
#define NMB0 496   // m-tiles in main GEMM (deterministic stats partials)
#define NMB1 38    // m-tiles in FC GEMM
#define RCH 16     // stage-A chunk size (m-tiles per chunk)
#define NCH0 (NMB0 / RCH)   // 31 chunks, exact

// ---------- bf16 helpers (RNE) ----------
DEV uint16_t f2bf(float f) {
    union { float f; uint32_t u; } v; v.f = f;
    uint32_t r = v.u + 0x7fffu + ((v.u >> 16) & 1u);
    return (uint16_t)(r >> 16);
}
DEV float bf2f(uint16_t h) {
    union { uint32_t u; float f; } v; v.u = ((uint32_t)h) << 16;
    return v.f;
}
DEV float bflo(uint32_t w) { union { uint32_t u; float f; } v; v.u = w << 16; return v.f; }
DEV float bfhi(uint32_t w) { union { uint32_t u; float f; } v; v.u = w & 0xffff0000u; return v.f; }

#if __has_builtin(__builtin_amdgcn_cvt_pk_bf16_f32)
typedef __bf16 bf16x2 __attribute__((ext_vector_type(2)));
DEV uint32_t pk2bf(float lo, float hi) {
    bf16x2 r = __builtin_amdgcn_cvt_pk_bf16_f32(lo, hi);
    return __builtin_bit_cast(uint32_t, r);
}
#else
DEV uint32_t pk2bf(float lo, float hi) {
    return (uint32_t)f2bf(lo) | ((uint32_t)f2bf(hi) << 16);
}
#endif

// ---------- async global->LDS, 16B per lane ----------
#if __has_builtin(__builtin_amdgcn_global_load_lds)
DEV void async16(const uint16_t* g, uint16_t* l) {
    __builtin_amdgcn_global_load_lds(
        (const __attribute__((address_space(1))) uint32_t*)g,
        (__attribute__((address_space(3))) uint32_t*)l, 16, 0, 0);
}
#else
DEV void async16(const uint16_t* g, uint16_t* l) {
    *(u16x8*)l = *(const u16x8*)g;
}
#endif

// ---------- wave-parallel 31x31 inclusive 2D prefix over buf[r*31+c] ----------
// 256 threads = 4 waves; each 32-lane half scans one row/col via Hillis-Steele
// (5 shfl_up steps) -> replaces 31 serial dependent LDS iterations per phase.
// Fixed tree order -> bit-deterministic. Column reads are stride-31 (odd) ->
// bank-conflict-free.
DEV void prefix2d_31(float* buf, int tid) {
    const int wv = tid >> 6;            // 0..3
    const int half = (tid >> 5) & 1;    // 0..1
    const int pos = tid & 31;           // 0..31 (pos 31 idle)
    // row scan
    #pragma unroll
    for (int p = 0; p < 4; ++p) {
        int row = p * 8 + wv * 2 + half;
        bool act = (row < 31) && (pos < 31);
        float v = act ? buf[row * 31 + pos] : 0.f;
        #pragma unroll
        for (int d = 1; d < 32; d <<= 1) {
            float o = __shfl_up(v, d, 32);
            if (pos >= d) v += o;
        }
        if (act) buf[row * 31 + pos] = v;
    }
    __syncthreads();
    // column scan
    #pragma unroll
    for (int p = 0; p < 4; ++p) {
        int col = p * 8 + wv * 2 + half;
        bool act = (col < 31) && (pos < 31);
        float v = act ? buf[pos * 31 + col] : 0.f;
        #pragma unroll
        for (int d = 1; d < 32; d <<= 1) {
            float o = __shfl_up(v, d, 32);
            if (pos >= d) v += o;
        }
        if (act) buf[pos * 31 + col] = v;
    }
    __syncthreads();
}

// ---------- transpose + bf16 cast: x (B,512,961) f32 -> xbt (B*992, 512) bf16 ----------
// rows n in [961,992) zeroed (GEMM pad rows -> zero output, stats exact).
__global__ void k_convert_x(const float* __restrict__ x, uint16_t* __restrict__ xbt) {
    __shared__ float tile[32][33];
    int b = blockIdx.z;
    int n0 = blockIdx.x * 32;
    int c0 = blockIdx.y * 32;
    int tx = threadIdx.x, ty = threadIdx.y;   // 32 x 8
    #pragma unroll
    for (int i = 0; i < 4; ++i) {
        int c = c0 + ty + 8 * i;
        int n = n0 + tx;
        float v = 0.f;
        if (n < 961) v = x[((size_t)b * 512 + c) * 961 + n];
        tile[ty + 8 * i][tx] = v;
    }
    __syncthreads();
    int idx = ty * 32 + tx;          // 0..255
    int c4 = (idx & 7) * 4;          // 0..28
    int nl = idx >> 3;               // 0..31
    int n = n0 + nl;                 // < 992 always (31*32 grid)
    ushort4 val;
    val.x = f2bf(tile[c4 + 0][nl]);
    val.y = f2bf(tile[c4 + 1][nl]);
    val.z = f2bf(tile[c4 + 2][nl]);
    val.w = f2bf(tile[c4 + 3][nl]);
    *(ushort4*)&xbt[((size_t)b * NS + n) * 512 + c0 + c4] = val;
}

// merged weight converts: wvkt[j][k] (1024x512 B^T) and wfct[j][k] (512x1024 B^T)
__global__ void k_convert_w(const float* __restrict__ wv, const float* __restrict__ wk,
                            const float* __restrict__ wfc,
                            uint16_t* __restrict__ wvkt, uint16_t* __restrict__ wfct) {
    int idx = blockIdx.x * 256 + threadIdx.x;   // 0 .. 1048575
    if (idx < 524288) {
        int j = idx >> 9, k = idx & 511;
        float v = (j < 512) ? wv[(size_t)k * 512 + j] : wk[(size_t)k * 512 + (j - 512)];
        wvkt[idx] = f2bf(v);
    } else {
        int t = idx - 524288;
        int j = t >> 10, k = t & 1023;
        wfct[t] = f2bf(wfc[(size_t)k * 512 + j]);
    }
}

// ---------- bf16 MFMA GEMM, 128x128 tile, BK=64 (two 32-k panels) ----------
// EPI=0: 1D swizzled grid; M = 64*NS (pad rows are zero); writes v_raw/k_raw
//        bf16 (B,512,NS) via LDS transpose + aligned 8B stores + per-tile stats partials
// EPI=1: 2D grid, M=4864 exact; writes fc_raw f32 (M,512) + per-tile stats partials
// Stats are DETERMINISTIC: each block writes a unique partial slot
// part[mb * NCOLS + col]; separate kernels reduce in fixed order. No atomics.
//
// LDS bank-conflict fix (rule #21: linear global_load_lds dest + inverse-swizzled
// SOURCE + swizzled READ): granule slot (m, kq) holds global granule
// (m, kq ^ ((m>>1)&3)); fragment read at m*32 + (quad^((m>>1)&3))*8.
// (Measured r4: conflicts 8.9M -> 1.0M, but time-neutral — T2 regime-gate:
// 2-phase critical path is stage+barrier, conflicts hidden. Kept: harmless.)
template<int K, int EPI>
__global__ __launch_bounds__(256, 4)
void k_gemm(const uint16_t* __restrict__ A, const uint16_t* __restrict__ Bt,
            uint16_t* __restrict__ out_v, uint16_t* __restrict__ out_k,
            float* __restrict__ out_f,
            float* __restrict__ part)
{
    __shared__ __align__(16) uint16_t sbuf[16384];   // 32 KB staging / epi-transpose
    __shared__ float sStat[512];                      // [wm][col] sum, +256 sq
    uint16_t* sA0 = sbuf;
    uint16_t* sA1 = sbuf + 4096;
    uint16_t* sB0 = sbuf + 8192;
    uint16_t* sB1 = sbuf + 12288;

    const int tid = threadIdx.x;
    const int wave = tid >> 6, lane = tid & 63;
    const int quad = lane >> 4, l16 = lane & 15;
    int m0, j0, mbi = 0;
    if constexpr (EPI == 0) {
        // XCD swizzle: same mb on same XCD for 8 consecutive rounds (A-tile L2 reuse)
        int lin = blockIdx.x;
        int xcd = lin & 7, rest = lin >> 3;
        int jb = rest & 7, mhi = rest >> 3;
        int mb = mhi * 8 + xcd;            // 0..495, grid exact (3968 blocks)
        m0 = mb * 128; j0 = jb * 128; mbi = mb;
    } else {
        m0 = blockIdx.y * 128; j0 = blockIdx.x * 128; mbi = blockIdx.y;
    }
    const int wm = wave >> 1, wj = wave & 1;

    const f32x4 fzero = {0.f, 0.f, 0.f, 0.f};
    f32x4 acc[4][4];
    #pragma unroll
    for (int i = 0; i < 4; ++i)
        #pragma unroll
        for (int j = 0; j < 4; ++j) acc[i][j] = fzero;

    const int c0 = tid;
    const int mA0 = c0 >> 2;
    const int sq0 = (c0 & 3) ^ ((mA0 >> 1) & 3);   // inverse-swizzled source granule
    const int c1 = tid + 256;
    const int mA1 = c1 >> 2;
    const int sq1 = (c1 & 3) ^ ((mA1 >> 1) & 3);

    const int KT = K / 64;
    for (int kt = 0; kt < KT; ++kt) {
        const uint16_t* Ak = A + (size_t)m0 * K + kt * 64;
        const uint16_t* Bk = Bt + (size_t)j0 * K + kt * 64;
        async16(Ak + (size_t)mA0 * K + sq0 * 8,      &sA0[c0 * 8]);
        async16(Ak + (size_t)mA1 * K + sq1 * 8,      &sA0[c1 * 8]);
        async16(Ak + (size_t)mA0 * K + 32 + sq0 * 8, &sA1[c0 * 8]);
        async16(Ak + (size_t)mA1 * K + 32 + sq1 * 8, &sA1[c1 * 8]);
        async16(Bk + (size_t)mA0 * K + sq0 * 8,      &sB0[c0 * 8]);
        async16(Bk + (size_t)mA1 * K + sq1 * 8,      &sB0[c1 * 8]);
        async16(Bk + (size_t)mA0 * K + 32 + sq0 * 8, &sB1[c0 * 8]);
        async16(Bk + (size_t)mA1 * K + 32 + sq1 * 8, &sB1[c1 * 8]);
        __syncthreads();
        #pragma unroll
        for (int p = 0; p < 2; ++p) {
            const uint16_t* pA = p ? sA1 : sA0;
            const uint16_t* pB = p ? sB1 : sB0;
            bf16x8 af[4], bfr[4];
            #pragma unroll
            for (int i = 0; i < 4; ++i) {
                int m = wm * 64 + i * 16 + l16;
                int qs = quad ^ ((m >> 1) & 3);
                u16x8 r = *(const u16x8*)&pA[m * 32 + qs * 8];
                af[i] = __builtin_bit_cast(bf16x8, r);
            }
            #pragma unroll
            for (int j = 0; j < 4; ++j) {
                int jj = wj * 64 + j * 16 + l16;
                int qs = quad ^ ((jj >> 1) & 3);
                u16x8 r = *(const u16x8*)&pB[jj * 32 + qs * 8];
                bfr[j] = __builtin_bit_cast(bf16x8, r);
            }
            #pragma unroll
            for (int i = 0; i < 4; ++i)
                #pragma unroll
                for (int j = 0; j < 4; ++j)
                    acc[i][j] = __builtin_amdgcn_mfma_f32_16x16x32_bf16(af[i], bfr[j], acc[i][j], 0, 0, 0);
        }
        __syncthreads();
    }

    // ---- column stats: deterministic (pad rows are exactly zero -> unconditional) ----
    #pragma unroll
    for (int j = 0; j < 4; ++j) {
        const int col_local = wj * 64 + j * 16 + l16;
        float ls = 0.f, lq = 0.f;
        #pragma unroll
        for (int i = 0; i < 4; ++i) {
            #pragma unroll
            for (int reg = 0; reg < 4; ++reg) {
                const float val = acc[i][j][reg];
                ls += val; lq += val * val;
                if constexpr (EPI == 1) {
                    const int r = m0 + wm * 64 + i * 16 + quad * 4 + reg;
                    out_f[(size_t)r * 512 + (j0 + col_local)] = val;
                }
            }
        }
        ls += __shfl_xor(ls, 16); lq += __shfl_xor(lq, 16);
        ls += __shfl_xor(ls, 32); lq += __shfl_xor(lq, 32);
        if (quad == 0) {                      // unique writer per (wm, col_local)
            sStat[wm * 128 + col_local] = ls;
            sStat[256 + wm * 128 + col_local] = lq;
        }
    }
    __syncthreads();
    if (tid < 128) {                          // fixed-order combine wm=0 then wm=1
        float s = sStat[tid] + sStat[128 + tid];
        float q = sStat[256 + tid] + sStat[384 + tid];
        if constexpr (EPI == 0) {
            part[(size_t)mbi * 1024 + (j0 + tid)] = s;
            part[(size_t)NMB0 * 1024 + (size_t)mbi * 1024 + (j0 + tid)] = q;
        } else {
            part[(size_t)mbi * 512 + (j0 + tid)] = s;
            part[(size_t)NMB1 * 512 + (size_t)mbi * 512 + (j0 + tid)] = q;
        }
    }

    if constexpr (EPI == 0) {
        // ---- LDS transpose -> aligned 8B coalesced stores ----
        // Tile: 64 cols x 128 rows, col-major, row stride 136 ushorts.
        #pragma unroll
        for (int ch = 0; ch < 2; ++ch) {
            if (wj == ch) {
                #pragma unroll
                for (int j = 0; j < 4; ++j) {
                    const int c = j * 16 + l16;
                    #pragma unroll
                    for (int i = 0; i < 4; ++i) {
                        const int rloc = wm * 64 + i * 16 + quad * 4;
                        uint2 pp;
                        pp.x = pk2bf(acc[i][j][0], acc[i][j][1]);
                        pp.y = pk2bf(acc[i][j][2], acc[i][j][3]);
                        *(uint2*)&sbuf[c * 136 + rloc] = pp;
                    }
                }
            }
            __syncthreads();
            const int jg = j0 + ch * 64;                 // block-uniform
            uint16_t* const outp = (jg < 512) ? out_v : out_k;
            const int jbase = (jg < 512) ? jg : jg - 512;
            #pragma unroll
            for (int s = 0; s < 8; ++s) {
                const int chunk = tid + 256 * s;         // 2048 chunks
                const int c = chunk >> 5, q = chunk & 31;
                uint2 val = *(const uint2*)&sbuf[c * 136 + q * 4];
                const int r = m0 + q * 4;
                const unsigned bb_ = (unsigned)r / (unsigned)NS;
                const unsigned nn = (unsigned)r - bb_ * (unsigned)NS;  // ≡0 mod 4
                *(uint2*)&outp[((size_t)bb_ * 512 + jbase + c) * NS + nn] = val;
            }
            __syncthreads();
        }
    }
}

// ---------- deterministic stats reduction, two-stage, fixed order ----------
// Stage A: chunk of RCH m-tiles per block-row; full unroll -> batched loads.
// part layout: [nmb][NC] sums then [nmb][NC] sq. pp layout: [NCH][NC] + [NCH][NC].
template<int NMB, int NC>
__global__ void k_redA(const float* __restrict__ part, float* __restrict__ pp)
{
    static_assert(NMB % RCH == 0, "exact chunks");
    int col = blockIdx.x * 256 + threadIdx.x;
    int cz = blockIdx.y;
    int i0 = cz * RCH;
    float s = 0.f, q = 0.f;
    #pragma unroll
    for (int k = 0; k < RCH; ++k) {
        int i = i0 + k;
        s += part[(size_t)i * NC + col];
        q += part[(size_t)(NMB + i) * NC + col];
    }
    constexpr int nch = NMB / RCH;
    pp[(size_t)cz * NC + col] = s;
    pp[(size_t)(nch + cz) * NC + col] = q;
}

// Stage B: sum the chunk partials in fixed order (fully unrolled).
template<int NCH, int NC>
__global__ void k_redB(const float* __restrict__ pp, float* __restrict__ osum,
                       float* __restrict__ osq)
{
    int col = blockIdx.x * 256 + threadIdx.x;
    float s = 0.f, q = 0.f;
    #pragma unroll
    for (int k = 0; k < NCH; ++k) {
        s += pp[(size_t)k * NC + col];
        q += pp[(size_t)(NCH + k) * NC + col];
    }
    osum[col] = s;
    osq[col] = q;
}

// Small single-stage reduce (FC stats): loop fully unrolled -> loads batched.
template<int NMB, int NC>
__global__ void k_redsmall(const float* __restrict__ part, float* __restrict__ osum,
                           float* __restrict__ osq)
{
    int col = blockIdx.x * 256 + threadIdx.x;
    float s = 0.f, q = 0.f;
    #pragma unroll
    for (int i = 0; i < NMB; ++i) {
        s += part[(size_t)i * NC + col];
        q += part[(size_t)(NMB + i) * NC + col];
    }
    osum[col] = s;
    osq[col] = q;
}

// ---------- attention: per (b,h) softmax over 961 + per-head window means ----------
__global__ void k_attn(const uint16_t* __restrict__ kraw,
                       const float* __restrict__ colsum, const float* __restrict__ colsq,
                       const float* __restrict__ g_kn, const float* __restrict__ b_kn,
                       float* __restrict__ attn, float* __restrict__ maw)
{
    __shared__ float qa[64];
    __shared__ float s_qb;
    __shared__ float att[NS];
    __shared__ float red[8];

    int bh = blockIdx.x;          // b*8 + h
    int b = bh >> 3, h = bh & 7;
    int tid = threadIdx.x;        // 256
    constexpr float invM = 1.f / 61504.f;

    if (tid < 64) {               // BN affine + center-pixel query
        int c = h * 64 + tid;
        float mean = colsum[512 + c] * invM;
        float q_ = colsq[512 + c] * invM;
        float a = g_kn[c] * rsqrtf(q_ - mean * mean + 1e-5f);
        float bb = b_kn[c] - mean * a;
        float kr = bf2f(kraw[((size_t)b * 512 + c) * NS + 480]);
        float qv = kr * a + bb;
        qa[tid] = qv * a;
        float qb = qv * bb;
        for (int off = 32; off; off >>= 1) qb += __shfl_down(qb, off);
        if (tid == 0) s_qb = qb;
    }
    __syncthreads();

    const int n4 = tid * 4;
    const bool active = n4 < 961;
    float a0 = 0.f, a1 = 0.f, a2 = 0.f, a3 = 0.f;
    if (active) {
        const uint16_t* kp = kraw + ((size_t)b * 512 + h * 64) * NS + n4;
        #pragma unroll 16
        for (int dd = 0; dd < 64; ++dd) {
            uint2 kk = *(const uint2*)(kp + (size_t)dd * NS);
            float q = qa[dd];
            a0 += q * bflo(kk.x);
            a1 += q * bfhi(kk.x);
            a2 += q * bflo(kk.y);
            a3 += q * bfhi(kk.y);
        }
    }
    float lg[4] = {a0, a1, a2, a3};
    float lmax = -1e30f;
    #pragma unroll
    for (int i = 0; i < 4; ++i) {
        lg[i] = (lg[i] + s_qb) * 0.125f;
        if (n4 + i < 961) lmax = fmaxf(lmax, lg[i]);
    }
    for (int off = 32; off; off >>= 1) lmax = fmaxf(lmax, __shfl_xor(lmax, off));
    if ((tid & 63) == 0) red[tid >> 6] = lmax;
    __syncthreads();
    float bmax = fmaxf(fmaxf(red[0], red[1]), fmaxf(red[2], red[3]));

    float lsum = 0.f;
    #pragma unroll
    for (int i = 0; i < 4; ++i) {
        float e = (n4 + i < 961) ? __expf(lg[i] - bmax) : 0.f;
        lg[i] = e;
        lsum += e;
    }
    for (int off = 32; off; off >>= 1) lsum += __shfl_xor(lsum, off);
    if ((tid & 63) == 0) red[4 + (tid >> 6)] = lsum;
    __syncthreads();
    float inv = 1.f / (red[4] + red[5] + red[6] + red[7]);
    if (active) {
        f32x4 v = {lg[0] * inv, lg[1] * inv, lg[2] * inv, lg[3] * inv};
        *(f32x4*)&att[n4] = v;
        *(f32x4*)&attn[(size_t)bh * NS + n4] = v;
    }
    __syncthreads();

    // 31x31 inclusive 2D prefix in LDS (wave-parallel shuffle scan)
    prefix2d_31(att, tid);

    if (tid < 75) {
        int i = tid / 5 + 1, t = tid % 5;
        const int m = 15;
        int r0, r1, cc0, cc1;
        switch (t) {
            case 0: r0 = m - i; r1 = m + i + 1; cc0 = m - i; cc1 = m + i + 1; break;
            case 1: r0 = m - i; r1 = m + 1;     cc0 = m - i; cc1 = m + i + 1; break;
            case 2: r0 = m;     r1 = m + i + 1; cc0 = m - i; cc1 = m + i + 1; break;
            case 3: r0 = m - i; r1 = m + i + 1; cc0 = m - i; cc1 = m + 1;     break;
            default:r0 = m - i; r1 = m + i + 1; cc0 = m;     cc1 = m + i + 1; break;
        }
        auto S = [&](int r, int c) -> float { return (r < 0 || c < 0) ? 0.f : att[r * 31 + c]; };
        float box = S(r1 - 1, cc1 - 1) - S(r0 - 1, cc1 - 1) - S(r1 - 1, cc0 - 1) + S(r0 - 1, cc0 - 1);
        float cnt = (float)((r1 - r0) * (cc1 - cc0));
        maw[(size_t)bh * 75 + tid] = box / cnt;
    }
}

// ---------- window box means per (b,c); BN affine for v computed inline ----------
__global__ void k_winbox(const uint16_t* __restrict__ vraw,
                         const float* __restrict__ colsum, const float* __restrict__ colsq,
                         const float* __restrict__ g_vn, const float* __restrict__ b_vn,
                         const float* __restrict__ attn, const float* __restrict__ maw,
                         float* __restrict__ y)
{
    __shared__ float xw[NS];
    __shared__ float s_center;
    int bc = blockIdx.x;            // b*512 + c
    int b = bc >> 9, c = bc & 511;
    int h = c >> 6;
    int tid = threadIdx.x;          // 256
    constexpr float invM = 1.f / 61504.f;
    float mean = colsum[c] * invM;
    float q_ = colsq[c] * invM;
    float a = g_vn[c] * rsqrtf(q_ - mean * mean + 1e-5f);
    float bb = b_vn[c] - mean * a;
    const uint16_t* vp = vraw + (size_t)bc * NS;
    const float* ap = attn + (size_t)(b * 8 + h) * NS;
    int n4 = tid * 4;
    if (n4 < 961) {
        uint2 kk = *(const uint2*)(vp + n4);
        f32x4 at = *(const f32x4*)(ap + n4);
        f32x4 v;
        v[0] = fmaxf(bflo(kk.x) * a + bb, 0.f) * at[0];
        v[1] = fmaxf(bfhi(kk.x) * a + bb, 0.f) * at[1];
        v[2] = fmaxf(bflo(kk.y) * a + bb, 0.f) * at[2];
        v[3] = fmaxf(bfhi(kk.y) * a + bb, 0.f) * at[3];
        *(f32x4*)&xw[n4] = v;
    }
    __syncthreads();
    if (tid == 0) s_center = xw[480];
    __syncthreads();

    // 31x31 inclusive 2D prefix in LDS (wave-parallel shuffle scan)
    prefix2d_31(xw, tid);

    if (tid < 75) {
        int i = tid / 5 + 1, t = tid % 5;
        const int m = 15;
        int r0, r1, cc0, cc1;
        switch (t) {
            case 0: r0 = m - i; r1 = m + i + 1; cc0 = m - i; cc1 = m + i + 1; break;
            case 1: r0 = m - i; r1 = m + 1;     cc0 = m - i; cc1 = m + i + 1; break;
            case 2: r0 = m;     r1 = m + i + 1; cc0 = m - i; cc1 = m + i + 1; break;
            case 3: r0 = m - i; r1 = m + i + 1; cc0 = m - i; cc1 = m + 1;     break;
            default:r0 = m - i; r1 = m + i + 1; cc0 = m;     cc1 = m + i + 1; break;
        }
        auto S = [&](int r, int cc) -> float { return (r < 0 || cc < 0) ? 0.f : xw[r * 31 + cc]; };
        float box = S(r1 - 1, cc1 - 1) - S(r0 - 1, cc1 - 1) - S(r1 - 1, cc0 - 1) + S(r0 - 1, cc0 - 1);
        float cnt = (float)((r1 - r0) * (cc1 - cc0));
        float mx = box / cnt;
        float ma = maw[(size_t)(b * 8 + h) * 75 + tid];
        y[((size_t)b * 76 + 1 + tid) * 512 + c] = mx / (ma + 1e-16f);
    }
    if (tid == 96) y[((size_t)b * 76) * 512 + c] = s_center;
}

// ---------- row L2-normalize y, build yy = [x0_bf16 | bf16(y/||y||)] ----------
__global__ void k_build_yy(const float* __restrict__ y, const uint16_t* __restrict__ xbt,
                           uint16_t* __restrict__ yy)
{
    __shared__ float red[4];
    int row = blockIdx.x;           // b*76 + r
    int b = row / 76;
    int tid = threadIdx.x;          // 256
    const float* yp = y + (size_t)row * 512;
    float v0 = yp[tid], v1 = yp[tid + 256];
    float ss = v0 * v0 + v1 * v1;
    for (int off = 32; off; off >>= 1) ss += __shfl_xor(ss, off);
    if ((tid & 63) == 0) red[tid >> 6] = ss;
    __syncthreads();
    float tot = red[0] + red[1] + red[2] + red[3];
    float inv = 1.f / fmaxf(sqrtf(tot), 1e-12f);
    uint16_t* op = yy + (size_t)row * 1024;
    const uint16_t* x0p = xbt + ((size_t)b * NS + 480) * 512;
    op[tid]           = x0p[tid];
    op[tid + 256]     = x0p[tid + 256];
    op[512 + tid]       = f2bf(v0 * inv);
    op[512 + tid + 256] = f2bf(v1 * inv);
}

// ---------- final BN + relu (BN affine inline from stats) ----------
__global__ void k_fcout(const float* __restrict__ fcraw,
                        const float* __restrict__ colsum, const float* __restrict__ colsq,
                        const float* __restrict__ g, const float* __restrict__ be,
                        float* __restrict__ out)
{
    size_t idx = (size_t)blockIdx.x * 256 + threadIdx.x;
    if (idx < (size_t)4864 * 512) {
        int j = (int)(idx & 511);
        constexpr float invM = 1.f / 4864.f;
        float mean = colsum[j] * invM;
        float q_ = colsq[j] * invM;
        float a = g[j] * rsqrtf(q_ - mean * mean + 1e-5f);
        float bb = be[j] - mean * a;
        out[idx] = fmaxf(fcraw[idx] * a + bb, 0.f);
    }
}

extern "C" void kernel_launch(void* const* d_in, const int* in_sizes, int n_in,
                              void* d_out, int out_size, void* d_ws, size_t ws_size,
                              hipStream_t stream)
{
    (void)in_sizes; (void)n_in; (void)out_size; (void)ws_size;
    const float* x    = (const float*)d_in[0];
    const float* w_v  = (const float*)d_in[1];
    const float* g_vn = (const float*)d_in[3];
    const float* b_vn = (const float*)d_in[4];
    const float* w_k  = (const float*)d_in[5];
    const float* g_kn = (const float*)d_in[7];
    const float* b_kn = (const float*)d_in[8];
    const float* w_fc = (const float*)d_in[9];
    const float* g_fcn = (const float*)d_in[11];
    const float* b_fcn = (const float*)d_in[12];
    float* out = (float*)d_out;

    char* base = (char*)d_ws;
    size_t off = 0;
    auto alloc = [&](size_t bytes) -> void* {
        void* p = base + off;
        off += (bytes + 255) & ~(size_t)255;
        return p;
    };
    uint16_t* xbt  = (uint16_t*)alloc((size_t)64 * NS * 512 * 2);   // padded rows zeroed
    uint16_t* wvkt = (uint16_t*)alloc((size_t)1024 * 512 * 2);
    uint16_t* wfct = (uint16_t*)alloc((size_t)512 * 1024 * 2);
    uint16_t* vraw = (uint16_t*)alloc((size_t)64 * 512 * NS * 2);
    uint16_t* kraw = (uint16_t*)alloc((size_t)64 * 512 * NS * 2);
    float* stats   = (float*)alloc(3072 * 4);   // vk sum[1024], vk sq[1024], fc sum[512], fc sq[512]
    float* attn    = (float*)alloc((size_t)512 * NS * 4);
    float* maw     = (float*)alloc((size_t)512 * 75 * 4);
    float* y       = (float*)alloc((size_t)64 * 76 * 512 * 4);
    uint16_t* yy   = (uint16_t*)alloc((size_t)4864 * 1024 * 2);
    float* fcraw   = (float*)alloc((size_t)4864 * 512 * 4);
    float* part0   = (float*)alloc((size_t)2 * NMB0 * 1024 * 4);    // deterministic stat partials
    float* part1   = (float*)alloc((size_t)2 * NMB1 * 512 * 4);
    float* pp0     = (float*)alloc((size_t)2 * NCH0 * 1024 * 4);    // stage-A chunk partials

    k_convert_x<<<dim3(31, 16, 64), dim3(32, 8), 0, stream>>>(x, xbt);
    k_convert_w<<<4096, 256, 0, stream>>>(w_v, w_k, w_fc, wvkt, wfct);

    // 62*8*8 = 3968 blocks; kernel derives (m,j) with XCD-affine swizzle (496 m-tiles, exact)
    k_gemm<512, 0><<<3968, 256, 0, stream>>>(xbt, wvkt, vraw, kraw, nullptr, part0);
    k_redA<NMB0, 1024><<<dim3(4, NCH0), 256, 0, stream>>>(part0, pp0);
    k_redB<NCH0, 1024><<<4, 256, 0, stream>>>(pp0, stats, stats + 1024);

    k_attn<<<512, 256, 0, stream>>>(kraw, stats, stats + 1024, g_kn, b_kn, attn, maw);
    k_winbox<<<64 * 512, 256, 0, stream>>>(vraw, stats, stats + 1024, g_vn, b_vn, attn, maw, y);
    k_build_yy<<<4864, 256, 0, stream>>>(y, xbt, yy);

    k_gemm<1024, 1><<<dim3(4, 38), 256, 0, stream>>>(yy, wfct, nullptr, nullptr, fcraw, part1);
    k_redsmall<NMB1, 512><<<2, 256, 0, stream>>>(part1, stats + 2048, stats + 2560);
    k_fcout<<<9728, 256, 0, stream>>>(fcraw, stats + 2048, stats + 2560, g_fcn, b_fcn, out);
}

// Round 6
// 438.630 us; speedup vs baseline: 1.0739x; 1.0739x over previous
//
#include <hip/hip_runtime.h>
#include <stdint.h>

#define DEV __device__ __forceinline__

typedef __bf16 bf16x8 __attribute__((ext_vector_type(8)));
typedef unsigned short u16x8 __attribute__((ext_vector_type(8)));
typedef float f32x4 __attribute__((ext_vector_type(4)));

// n-dimension padded stride: 992 = 31*32 -> NS*2 bytes ≡ 0 mod 64 (aligned
// epilogue segments), 64*NS/128 = 496 m-tiles divisible by 8.
#define NS 992
#define NMB0 496   // m-tiles in main GEMM (deterministic stats partials)
#define NMB1 38    // m-tiles in FC GEMM
#define RCH 16     // stage-A chunk size (m-tiles per chunk)
#define NCH0 (NMB0 / RCH)   // 31 chunks, exact

// ---------- bf16 helpers (RNE) ----------
DEV uint16_t f2bf(float f) {
    union { float f; uint32_t u; } v; v.f = f;
    uint32_t r = v.u + 0x7fffu + ((v.u >> 16) & 1u);
    return (uint16_t)(r >> 16);
}
DEV float bf2f(uint16_t h) {
    union { uint32_t u; float f; } v; v.u = ((uint32_t)h) << 16;
    return v.f;
}
DEV float bflo(uint32_t w) { union { uint32_t u; float f; } v; v.u = w << 16; return v.f; }
DEV float bfhi(uint32_t w) { union { uint32_t u; float f; } v; v.u = w & 0xffff0000u; return v.f; }

#if __has_builtin(__builtin_amdgcn_cvt_pk_bf16_f32)
typedef __bf16 bf16x2 __attribute__((ext_vector_type(2)));
DEV uint32_t pk2bf(float lo, float hi) {
    bf16x2 r = __builtin_amdgcn_cvt_pk_bf16_f32(lo, hi);
    return __builtin_bit_cast(uint32_t, r);
}
#else
DEV uint32_t pk2bf(float lo, float hi) {
    return (uint32_t)f2bf(lo) | ((uint32_t)f2bf(hi) << 16);
}
#endif

// ---------- async global->LDS, 16B per lane ----------
#if __has_builtin(__builtin_amdgcn_global_load_lds)
DEV void async16(const uint16_t* g, uint16_t* l) {
    __builtin_amdgcn_global_load_lds(
        (const __attribute__((address_space(1))) uint32_t*)g,
        (__attribute__((address_space(3))) uint32_t*)l, 16, 0, 0);
}
#else
DEV void async16(const uint16_t* g, uint16_t* l) {
    *(u16x8*)l = *(const u16x8*)g;
}
#endif

// ---------- transpose + bf16 cast: x (B,512,961) f32 -> xbt (B*992, 512) bf16 ----------
// rows n in [961,992) zeroed (GEMM pad rows -> zero output, stats exact).
__global__ void k_convert_x(const float* __restrict__ x, uint16_t* __restrict__ xbt) {
    __shared__ float tile[32][33];
    int b = blockIdx.z;
    int n0 = blockIdx.x * 32;
    int c0 = blockIdx.y * 32;
    int tx = threadIdx.x, ty = threadIdx.y;   // 32 x 8
    #pragma unroll
    for (int i = 0; i < 4; ++i) {
        int c = c0 + ty + 8 * i;
        int n = n0 + tx;
        float v = 0.f;
        if (n < 961) v = x[((size_t)b * 512 + c) * 961 + n];
        tile[ty + 8 * i][tx] = v;
    }
    __syncthreads();
    int idx = ty * 32 + tx;          // 0..255
    int c4 = (idx & 7) * 4;          // 0..28
    int nl = idx >> 3;               // 0..31
    int n = n0 + nl;                 // < 992 always (31*32 grid)
    ushort4 val;
    val.x = f2bf(tile[c4 + 0][nl]);
    val.y = f2bf(tile[c4 + 1][nl]);
    val.z = f2bf(tile[c4 + 2][nl]);
    val.w = f2bf(tile[c4 + 3][nl]);
    *(ushort4*)&xbt[((size_t)b * NS + n) * 512 + c0 + c4] = val;
}

// merged weight converts: wvkt[j][k] (1024x512 B^T) and wfct[j][k] (512x1024 B^T)
__global__ void k_convert_w(const float* __restrict__ wv, const float* __restrict__ wk,
                            const float* __restrict__ wfc,
                            uint16_t* __restrict__ wvkt, uint16_t* __restrict__ wfct) {
    int idx = blockIdx.x * 256 + threadIdx.x;   // 0 .. 1048575
    if (idx < 524288) {
        int j = idx >> 9, k = idx & 511;
        float v = (j < 512) ? wv[(size_t)k * 512 + j] : wk[(size_t)k * 512 + (j - 512)];
        wvkt[idx] = f2bf(v);
    } else {
        int t = idx - 524288;
        int j = t >> 10, k = t & 1023;
        wfct[t] = f2bf(wfc[(size_t)k * 512 + j]);
    }
}

// ---------- bf16 MFMA GEMM, 128x128 tile, BK=32 double-buffered pipeline ----------
// T3 "minimum 2-phase" schedule: per 32-k panel { stage(p+1) into other buf;
// ds_read+MFMA panel p; s_waitcnt vmcnt(0); raw s_barrier }. Next-panel HBM/L3
// latency hides under current panel's compute; no full-drain __syncthreads in
// the K-loop. LDS footprint unchanged (4 x 8KB staging).
// Stats DETERMINISTIC: unique partial slot per block, fixed-order reduce after.
// Granule swizzle (rule #21): slot (m,kq) holds global granule (m, kq^((m>>1)&3));
// read at m*32 + (quad^((m>>1)&3))*8 -> 2-way LDS aliasing (free).
template<int K, int EPI>
__global__ __launch_bounds__(256, 4)
void k_gemm(const uint16_t* __restrict__ A, const uint16_t* __restrict__ Bt,
            uint16_t* __restrict__ out_v, uint16_t* __restrict__ out_k,
            float* __restrict__ out_f,
            float* __restrict__ part)
{
    __shared__ __align__(16) uint16_t sbuf[16384];   // 32 KB: A0,B0,A1,B1 / epi-transpose
    __shared__ float sStat[512];                      // [wm][col] sum, +256 sq
    uint16_t* const sA0 = sbuf;
    uint16_t* const sB0 = sbuf + 4096;
    uint16_t* const sA1 = sbuf + 8192;
    uint16_t* const sB1 = sbuf + 12288;

    const int tid = threadIdx.x;
    const int wave = tid >> 6, lane = tid & 63;
    const int quad = lane >> 4, l16 = lane & 15;
    int m0, j0, mbi = 0;
    if constexpr (EPI == 0) {
        // XCD swizzle: same mb on same XCD for 8 consecutive rounds (A-tile L2 reuse)
        int lin = blockIdx.x;
        int xcd = lin & 7, rest = lin >> 3;
        int jb = rest & 7, mhi = rest >> 3;
        int mb = mhi * 8 + xcd;            // 0..495, grid exact (3968 blocks)
        m0 = mb * 128; j0 = jb * 128; mbi = mb;
    } else {
        m0 = blockIdx.y * 128; j0 = blockIdx.x * 128; mbi = blockIdx.y;
    }
    const int wm = wave >> 1, wj = wave & 1;

    const f32x4 fzero = {0.f, 0.f, 0.f, 0.f};
    f32x4 acc[4][4];
    #pragma unroll
    for (int i = 0; i < 4; ++i)
        #pragma unroll
        for (int j = 0; j < 4; ++j) acc[i][j] = fzero;

    const int c0 = tid;
    const int mA0 = c0 >> 2;
    const int sq0 = (c0 & 3) ^ ((mA0 >> 1) & 3);   // inverse-swizzled source granule
    const int c1 = tid + 256;
    const int mA1 = c1 >> 2;
    const int sq1 = (c1 & 3) ^ ((mA1 >> 1) & 3);

    // stage one 128x32 A-panel + B-panel (4 async16/thread) for k-panel p
    auto stage = [&](int p, uint16_t* dA, uint16_t* dB) {
        const uint16_t* Ak = A + (size_t)m0 * K + p * 32;
        const uint16_t* Bk = Bt + (size_t)j0 * K + p * 32;
        async16(Ak + (size_t)mA0 * K + sq0 * 8, &dA[c0 * 8]);
        async16(Ak + (size_t)mA1 * K + sq1 * 8, &dA[c1 * 8]);
        async16(Bk + (size_t)mA0 * K + sq0 * 8, &dB[c0 * 8]);
        async16(Bk + (size_t)mA1 * K + sq1 * 8, &dB[c1 * 8]);
    };
    auto compute = [&](const uint16_t* pA, const uint16_t* pB) {
        bf16x8 af[4], bfr[4];
        #pragma unroll
        for (int i = 0; i < 4; ++i) {
            int m = wm * 64 + i * 16 + l16;
            int qs = quad ^ ((m >> 1) & 3);
            u16x8 r = *(const u16x8*)&pA[m * 32 + qs * 8];
            af[i] = __builtin_bit_cast(bf16x8, r);
        }
        #pragma unroll
        for (int j = 0; j < 4; ++j) {
            int jj = wj * 64 + j * 16 + l16;
            int qs = quad ^ ((jj >> 1) & 3);
            u16x8 r = *(const u16x8*)&pB[jj * 32 + qs * 8];
            bfr[j] = __builtin_bit_cast(bf16x8, r);
        }
        #pragma unroll
        for (int i = 0; i < 4; ++i)
            #pragma unroll
            for (int j = 0; j < 4; ++j)
                acc[i][j] = __builtin_amdgcn_mfma_f32_16x16x32_bf16(af[i], bfr[j], acc[i][j], 0, 0, 0);
    };
    auto panel_sync = [&]() {
        asm volatile("s_waitcnt vmcnt(0)" ::: "memory");
        __builtin_amdgcn_s_barrier();
        __builtin_amdgcn_sched_barrier(0);
    };

    constexpr int NP = K / 32;   // even (16 or 32)
    stage(0, sA0, sB0);
    panel_sync();
    for (int p = 0; p < NP; p += 2) {
        stage(p + 1, sA1, sB1);          // overlaps compute of panel p
        compute(sA0, sB0);
        panel_sync();                    // drain p+1 loads (landed under compute), join waves
        if (p + 2 < NP) stage(p + 2, sA0, sB0);
        compute(sA1, sB1);
        panel_sync();
    }

    // ---- column stats: deterministic (pad rows are exactly zero -> unconditional) ----
    #pragma unroll
    for (int j = 0; j < 4; ++j) {
        const int col_local = wj * 64 + j * 16 + l16;
        float ls = 0.f, lq = 0.f;
        #pragma unroll
        for (int i = 0; i < 4; ++i) {
            #pragma unroll
            for (int reg = 0; reg < 4; ++reg) {
                const float val = acc[i][j][reg];
                ls += val; lq += val * val;
                if constexpr (EPI == 1) {
                    const int r = m0 + wm * 64 + i * 16 + quad * 4 + reg;
                    out_f[(size_t)r * 512 + (j0 + col_local)] = val;
                }
            }
        }
        ls += __shfl_xor(ls, 16); lq += __shfl_xor(lq, 16);
        ls += __shfl_xor(ls, 32); lq += __shfl_xor(lq, 32);
        if (quad == 0) {                      // unique writer per (wm, col_local)
            sStat[wm * 128 + col_local] = ls;
            sStat[256 + wm * 128 + col_local] = lq;
        }
    }
    __syncthreads();
    if (tid < 128) {                          // fixed-order combine wm=0 then wm=1
        float s = sStat[tid] + sStat[128 + tid];
        float q = sStat[256 + tid] + sStat[384 + tid];
        if constexpr (EPI == 0) {
            part[(size_t)mbi * 1024 + (j0 + tid)] = s;
            part[(size_t)NMB0 * 1024 + (size_t)mbi * 1024 + (j0 + tid)] = q;
        } else {
            part[(size_t)mbi * 512 + (j0 + tid)] = s;
            part[(size_t)NMB1 * 512 + (size_t)mbi * 512 + (j0 + tid)] = q;
        }
    }

    if constexpr (EPI == 0) {
        // ---- LDS transpose -> aligned 8B coalesced stores ----
        // Tile: 64 cols x 128 rows, col-major, row stride 136 ushorts.
        #pragma unroll
        for (int ch = 0; ch < 2; ++ch) {
            if (wj == ch) {
                #pragma unroll
                for (int j = 0; j < 4; ++j) {
                    const int c = j * 16 + l16;
                    #pragma unroll
                    for (int i = 0; i < 4; ++i) {
                        const int rloc = wm * 64 + i * 16 + quad * 4;
                        uint2 pp;
                        pp.x = pk2bf(acc[i][j][0], acc[i][j][1]);
                        pp.y = pk2bf(acc[i][j][2], acc[i][j][3]);
                        *(uint2*)&sbuf[c * 136 + rloc] = pp;
                    }
                }
            }
            __syncthreads();
            const int jg = j0 + ch * 64;                 // block-uniform
            uint16_t* const outp = (jg < 512) ? out_v : out_k;
            const int jbase = (jg < 512) ? jg : jg - 512;
            #pragma unroll
            for (int s = 0; s < 8; ++s) {
                const int chunk = tid + 256 * s;         // 2048 chunks
                const int c = chunk >> 5, q = chunk & 31;
                uint2 val = *(const uint2*)&sbuf[c * 136 + q * 4];
                const int r = m0 + q * 4;
                const unsigned bb_ = (unsigned)r / (unsigned)NS;
                const unsigned nn = (unsigned)r - bb_ * (unsigned)NS;  // ≡0 mod 4
                *(uint2*)&outp[((size_t)bb_ * 512 + jbase + c) * NS + nn] = val;
            }
            __syncthreads();
        }
    }
}

// ---------- deterministic stats reduction, two-stage, fixed order ----------
template<int NMB, int NC>
__global__ void k_redA(const float* __restrict__ part, float* __restrict__ pp)
{
    static_assert(NMB % RCH == 0, "exact chunks");
    int col = blockIdx.x * 256 + threadIdx.x;
    int cz = blockIdx.y;
    int i0 = cz * RCH;
    float s = 0.f, q = 0.f;
    #pragma unroll
    for (int k = 0; k < RCH; ++k) {
        int i = i0 + k;
        s += part[(size_t)i * NC + col];
        q += part[(size_t)(NMB + i) * NC + col];
    }
    constexpr int nch = NMB / RCH;
    pp[(size_t)cz * NC + col] = s;
    pp[(size_t)(nch + cz) * NC + col] = q;
}

template<int NCH, int NC>
__global__ void k_redB(const float* __restrict__ pp, float* __restrict__ osum,
                       float* __restrict__ osq)
{
    int col = blockIdx.x * 256 + threadIdx.x;
    float s = 0.f, q = 0.f;
    #pragma unroll
    for (int k = 0; k < NCH; ++k) {
        s += pp[(size_t)k * NC + col];
        q += pp[(size_t)(NCH + k) * NC + col];
    }
    osum[col] = s;
    osq[col] = q;
}

template<int NMB, int NC>
__global__ void k_redsmall(const float* __restrict__ part, float* __restrict__ osum,
                           float* __restrict__ osq)
{
    int col = blockIdx.x * 256 + threadIdx.x;
    float s = 0.f, q = 0.f;
    #pragma unroll
    for (int i = 0; i < NMB; ++i) {
        s += part[(size_t)i * NC + col];
        q += part[(size_t)(NMB + i) * NC + col];
    }
    osum[col] = s;
    osq[col] = q;
}

// ---------- attention: per (b,h) softmax over 961 + per-head window means ----------
__global__ void k_attn(const uint16_t* __restrict__ kraw,
                       const float* __restrict__ colsum, const float* __restrict__ colsq,
                       const float* __restrict__ g_kn, const float* __restrict__ b_kn,
                       float* __restrict__ attn, float* __restrict__ maw)
{
    __shared__ float qa[64];
    __shared__ float s_qb;
    __shared__ float att[NS];
    __shared__ float red[8];

    int bh = blockIdx.x;          // b*8 + h
    int b = bh >> 3, h = bh & 7;
    int tid = threadIdx.x;        // 256
    constexpr float invM = 1.f / 61504.f;

    if (tid < 64) {               // BN affine + center-pixel query
        int c = h * 64 + tid;
        float mean = colsum[512 + c] * invM;
        float q_ = colsq[512 + c] * invM;
        float a = g_kn[c] * rsqrtf(q_ - mean * mean + 1e-5f);
        float bb = b_kn[c] - mean * a;
        float kr = bf2f(kraw[((size_t)b * 512 + c) * NS + 480]);
        float qv = kr * a + bb;
        qa[tid] = qv * a;
        float qb = qv * bb;
        for (int off = 32; off; off >>= 1) qb += __shfl_down(qb, off);
        if (tid == 0) s_qb = qb;
    }
    __syncthreads();

    const int n4 = tid * 4;
    const bool active = n4 < 961;
    float a0 = 0.f, a1 = 0.f, a2 = 0.f, a3 = 0.f;
    if (active) {
        const uint16_t* kp = kraw + ((size_t)b * 512 + h * 64) * NS + n4;
        #pragma unroll 16
        for (int dd = 0; dd < 64; ++dd) {
            uint2 kk = *(const uint2*)(kp + (size_t)dd * NS);
            float q = qa[dd];
            a0 += q * bflo(kk.x);
            a1 += q * bfhi(kk.x);
            a2 += q * bflo(kk.y);
            a3 += q * bfhi(kk.y);
        }
    }
    float lg[4] = {a0, a1, a2, a3};
    float lmax = -1e30f;
    #pragma unroll
    for (int i = 0; i < 4; ++i) {
        lg[i] = (lg[i] + s_qb) * 0.125f;
        if (n4 + i < 961) lmax = fmaxf(lmax, lg[i]);
    }
    for (int off = 32; off; off >>= 1) lmax = fmaxf(lmax, __shfl_xor(lmax, off));
    if ((tid & 63) == 0) red[tid >> 6] = lmax;
    __syncthreads();
    float bmax = fmaxf(fmaxf(red[0], red[1]), fmaxf(red[2], red[3]));

    float lsum = 0.f;
    #pragma unroll
    for (int i = 0; i < 4; ++i) {
        float e = (n4 + i < 961) ? __expf(lg[i] - bmax) : 0.f;
        lg[i] = e;
        lsum += e;
    }
    for (int off = 32; off; off >>= 1) lsum += __shfl_xor(lsum, off);
    if ((tid & 63) == 0) red[4 + (tid >> 6)] = lsum;
    __syncthreads();
    float inv = 1.f / (red[4] + red[5] + red[6] + red[7]);
    if (active) {
        f32x4 v = {lg[0] * inv, lg[1] * inv, lg[2] * inv, lg[3] * inv};
        *(f32x4*)&att[n4] = v;
        *(f32x4*)&attn[(size_t)bh * NS + n4] = v;
    }
    __syncthreads();

    // 31x31 inclusive 2D prefix in LDS (serial: TLP across 512 blocks hides it;
    // wave-parallel variant measured r5: 4x more issue work -> slower. Keep serial.)
    if (tid < 31) { float s = 0.f; for (int cc = 0; cc < 31; ++cc) { s += att[tid * 31 + cc]; att[tid * 31 + cc] = s; } }
    __syncthreads();
    if (tid < 31) { float s = 0.f; for (int rr = 0; rr < 31; ++rr) { s += att[rr * 31 + tid]; att[rr * 31 + tid] = s; } }
    __syncthreads();

    if (tid < 75) {
        int i = tid / 5 + 1, t = tid % 5;
        const int m = 15;
        int r0, r1, cc0, cc1;
        switch (t) {
            case 0: r0 = m - i; r1 = m + i + 1; cc0 = m - i; cc1 = m + i + 1; break;
            case 1: r0 = m - i; r1 = m + 1;     cc0 = m - i; cc1 = m + i + 1; break;
            case 2: r0 = m;     r1 = m + i + 1; cc0 = m - i; cc1 = m + i + 1; break;
            case 3: r0 = m - i; r1 = m + i + 1; cc0 = m - i; cc1 = m + 1;     break;
            default:r0 = m - i; r1 = m + i + 1; cc0 = m;     cc1 = m + i + 1; break;
        }
        auto S = [&](int r, int c) -> float { return (r < 0 || c < 0) ? 0.f : att[r * 31 + c]; };
        float box = S(r1 - 1, cc1 - 1) - S(r0 - 1, cc1 - 1) - S(r1 - 1, cc0 - 1) + S(r0 - 1, cc0 - 1);
        float cnt = (float)((r1 - r0) * (cc1 - cc0));
        maw[(size_t)bh * 75 + tid] = box / cnt;
    }
}

// ---------- window box means per (b,c); BN affine for v computed inline ----------
__global__ void k_winbox(const uint16_t* __restrict__ vraw,
                         const float* __restrict__ colsum, const float* __restrict__ colsq,
                         const float* __restrict__ g_vn, const float* __restrict__ b_vn,
                         const float* __restrict__ attn, const float* __restrict__ maw,
                         float* __restrict__ y)
{
    __shared__ float xw[NS];
    __shared__ float s_center;
    int bc = blockIdx.x;            // b*512 + c
    int b = bc >> 9, c = bc & 511;
    int h = c >> 6;
    int tid = threadIdx.x;          // 256
    constexpr float invM = 1.f / 61504.f;
    float mean = colsum[c] * invM;
    float q_ = colsq[c] * invM;
    float a = g_vn[c] * rsqrtf(q_ - mean * mean + 1e-5f);
    float bb = b_vn[c] - mean * a;
    const uint16_t* vp = vraw + (size_t)bc * NS;
    const float* ap = attn + (size_t)(b * 8 + h) * NS;
    int n4 = tid * 4;
    if (n4 < 961) {
        uint2 kk = *(const uint2*)(vp + n4);
        f32x4 at = *(const f32x4*)(ap + n4);
        f32x4 v;
        v[0] = fmaxf(bflo(kk.x) * a + bb, 0.f) * at[0];
        v[1] = fmaxf(bfhi(kk.x) * a + bb, 0.f) * at[1];
        v[2] = fmaxf(bflo(kk.y) * a + bb, 0.f) * at[2];
        v[3] = fmaxf(bfhi(kk.y) * a + bb, 0.f) * at[3];
        *(f32x4*)&xw[n4] = v;
    }
    __syncthreads();
    if (tid == 0) s_center = xw[480];
    __syncthreads();
    if (tid < 31) { float s = 0.f; for (int cc = 0; cc < 31; ++cc) { s += xw[tid * 31 + cc]; xw[tid * 31 + cc] = s; } }
    __syncthreads();
    if (tid < 31) { float s = 0.f; for (int rr = 0; rr < 31; ++rr) { s += xw[rr * 31 + tid]; xw[rr * 31 + tid] = s; } }
    __syncthreads();
    if (tid < 75) {
        int i = tid / 5 + 1, t = tid % 5;
        const int m = 15;
        int r0, r1, cc0, cc1;
        switch (t) {
            case 0: r0 = m - i; r1 = m + i + 1; cc0 = m - i; cc1 = m + i + 1; break;
            case 1: r0 = m - i; r1 = m + 1;     cc0 = m - i; cc1 = m + i + 1; break;
            case 2: r0 = m;     r1 = m + i + 1; cc0 = m - i; cc1 = m + i + 1; break;
            case 3: r0 = m - i; r1 = m + i + 1; cc0 = m - i; cc1 = m + 1;     break;
            default:r0 = m - i; r1 = m + i + 1; cc0 = m;     cc1 = m + i + 1; break;
        }
        auto S = [&](int r, int cc) -> float { return (r < 0 || cc < 0) ? 0.f : xw[r * 31 + cc]; };
        float box = S(r1 - 1, cc1 - 1) - S(r0 - 1, cc1 - 1) - S(r1 - 1, cc0 - 1) + S(r0 - 1, cc0 - 1);
        float cnt = (float)((r1 - r0) * (cc1 - cc0));
        float mx = box / cnt;
        float ma = maw[(size_t)(b * 8 + h) * 75 + tid];
        y[((size_t)b * 76 + 1 + tid) * 512 + c] = mx / (ma + 1e-16f);
    }
    if (tid == 96) y[((size_t)b * 76) * 512 + c] = s_center;
}

// ---------- row L2-normalize y, build yy = [x0_bf16 | bf16(y/||y||)] ----------
__global__ void k_build_yy(const float* __restrict__ y, const uint16_t* __restrict__ xbt,
                           uint16_t* __restrict__ yy)
{
    __shared__ float red[4];
    int row = blockIdx.x;           // b*76 + r
    int b = row / 76;
    int tid = threadIdx.x;          // 256
    const float* yp = y + (size_t)row * 512;
    float v0 = yp[tid], v1 = yp[tid + 256];
    float ss = v0 * v0 + v1 * v1;
    for (int off = 32; off; off >>= 1) ss += __shfl_xor(ss, off);
    if ((tid & 63) == 0) red[tid >> 6] = ss;
    __syncthreads();
    float tot = red[0] + red[1] + red[2] + red[3];
    float inv = 1.f / fmaxf(sqrtf(tot), 1e-12f);
    uint16_t* op = yy + (size_t)row * 1024;
    const uint16_t* x0p = xbt + ((size_t)b * NS + 480) * 512;
    op[tid]           = x0p[tid];
    op[tid + 256]     = x0p[tid + 256];
    op[512 + tid]       = f2bf(v0 * inv);
    op[512 + tid + 256] = f2bf(v1 * inv);
}

// ---------- final BN + relu (BN affine inline from stats) ----------
__global__ void k_fcout(const float* __restrict__ fcraw,
                        const float* __restrict__ colsum, const float* __restrict__ colsq,
                        const float* __restrict__ g, const float* __restrict__ be,
                        float* __restrict__ out)
{
    size_t idx = (size_t)blockIdx.x * 256 + threadIdx.x;
    if (idx < (size_t)4864 * 512) {
        int j = (int)(idx & 511);
        constexpr float invM = 1.f / 4864.f;
        float mean = colsum[j] * invM;
        float q_ = colsq[j] * invM;
        float a = g[j] * rsqrtf(q_ - mean * mean + 1e-5f);
        float bb = be[j] - mean * a;
        out[idx] = fmaxf(fcraw[idx] * a + bb, 0.f);
    }
}

extern "C" void kernel_launch(void* const* d_in, const int* in_sizes, int n_in,
                              void* d_out, int out_size, void* d_ws, size_t ws_size,
                              hipStream_t stream)
{
    (void)in_sizes; (void)n_in; (void)out_size; (void)ws_size;
    const float* x    = (const float*)d_in[0];
    const float* w_v  = (const float*)d_in[1];
    const float* g_vn = (const float*)d_in[3];
    const float* b_vn = (const float*)d_in[4];
    const float* w_k  = (const float*)d_in[5];
    const float* g_kn = (const float*)d_in[7];
    const float* b_kn = (const float*)d_in[8];
    const float* w_fc = (const float*)d_in[9];
    const float* g_fcn = (const float*)d_in[11];
    const float* b_fcn = (const float*)d_in[12];
    float* out = (float*)d_out;

    char* base = (char*)d_ws;
    size_t off = 0;
    auto alloc = [&](size_t bytes) -> void* {
        void* p = base + off;
        off += (bytes + 255) & ~(size_t)255;
        return p;
    };
    uint16_t* xbt  = (uint16_t*)alloc((size_t)64 * NS * 512 * 2);   // padded rows zeroed
    uint16_t* wvkt = (uint16_t*)alloc((size_t)1024 * 512 * 2);
    uint16_t* wfct = (uint16_t*)alloc((size_t)512 * 1024 * 2);
    uint16_t* vraw = (uint16_t*)alloc((size_t)64 * 512 * NS * 2);
    uint16_t* kraw = (uint16_t*)alloc((size_t)64 * 512 * NS * 2);
    float* stats   = (float*)alloc(3072 * 4);   // vk sum[1024], vk sq[1024], fc sum[512], fc sq[512]
    float* attn    = (float*)alloc((size_t)512 * NS * 4);
    float* maw     = (float*)alloc((size_t)512 * 75 * 4);
    float* y       = (float*)alloc((size_t)64 * 76 * 512 * 4);
    uint16_t* yy   = (uint16_t*)alloc((size_t)4864 * 1024 * 2);
    float* fcraw   = (float*)alloc((size_t)4864 * 512 * 4);
    float* part0   = (float*)alloc((size_t)2 * NMB0 * 1024 * 4);    // deterministic stat partials
    float* part1   = (float*)alloc((size_t)2 * NMB1 * 512 * 4);
    float* pp0     = (float*)alloc((size_t)2 * NCH0 * 1024 * 4);    // stage-A chunk partials

    k_convert_x<<<dim3(31, 16, 64), dim3(32, 8), 0, stream>>>(x, xbt);
    k_convert_w<<<4096, 256, 0, stream>>>(w_v, w_k, w_fc, wvkt, wfct);

    // 62*8*8 = 3968 blocks; kernel derives (m,j) with XCD-affine swizzle (496 m-tiles, exact)
    k_gemm<512, 0><<<3968, 256, 0, stream>>>(xbt, wvkt, vraw, kraw, nullptr, part0);
    k_redA<NMB0, 1024><<<dim3(4, NCH0), 256, 0, stream>>>(part0, pp0);
    k_redB<NCH0, 1024><<<4, 256, 0, stream>>>(pp0, stats, stats + 1024);

    k_attn<<<512, 256, 0, stream>>>(kraw, stats, stats + 1024, g_kn, b_kn, attn, maw);
    k_winbox<<<64 * 512, 256, 0, stream>>>(vraw, stats, stats + 1024, g_vn, b_vn, attn, maw, y);
    k_build_yy<<<4864, 256, 0, stream>>>(y, xbt, yy);

    k_gemm<1024, 1><<<dim3(4, 38), 256, 0, stream>>>(yy, wfct, nullptr, nullptr, fcraw, part1);
    k_redsmall<NMB1, 512><<<2, 256, 0, stream>>>(part1, stats + 2048, stats + 2560);
    k_fcout<<<9728, 256, 0, stream>>>(fcraw, stats + 2048, stats + 2560, g_fcn, b_fcn, out);
}

// Round 8
// 438.016 us; speedup vs baseline: 1.0754x; 1.0014x over previous
//
#include <hip/hip_runtime.h>
#include <stdint.h>

#define DEV __device__ __forceinline__

typedef __bf16 bf16x8 __attribute__((ext_vector_type(8)));
typedef unsigned short u16x8 __attribute__((ext_vector_type(8)));
typedef float f32x4 __attribute__((ext_vector_type(4)));

// n-dimension padded stride: 992 = 31*32 -> NS*2 bytes ≡ 0 mod 64 (aligned
// epilogue segments), 64*NS/128 = 496 m-tiles divisible by 8.
#define NS 992
#define NMB0 496   // m-tiles in main GEMM (deterministic stats partials)
#define NMB1 38    // m-tiles in FC GEMM
#define RCH 16     // stage-A chunk size (m-tiles per chunk)
#define NCH0 (NMB0 / RCH)   // 31 chunks, exact

// ---------- bf16 helpers (RNE) ----------
DEV uint16_t f2bf(float f) {
    union { float f; uint32_t u; } v; v.f = f;
    uint32_t r = v.u + 0x7fffu + ((v.u >> 16) & 1u);
    return (uint16_t)(r >> 16);
}
DEV float bf2f(uint16_t h) {
    union { uint32_t u; float f; } v; v.u = ((uint32_t)h) << 16;
    return v.f;
}
DEV float bflo(uint32_t w) { union { uint32_t u; float f; } v; v.u = w << 16; return v.f; }
DEV float bfhi(uint32_t w) { union { uint32_t u; float f; } v; v.u = w & 0xffff0000u; return v.f; }

#if __has_builtin(__builtin_amdgcn_cvt_pk_bf16_f32)
typedef __bf16 bf16x2 __attribute__((ext_vector_type(2)));
DEV uint32_t pk2bf(float lo, float hi) {
    bf16x2 r = __builtin_amdgcn_cvt_pk_bf16_f32(lo, hi);
    return __builtin_bit_cast(uint32_t, r);
}
#else
DEV uint32_t pk2bf(float lo, float hi) {
    return (uint32_t)f2bf(lo) | ((uint32_t)f2bf(hi) << 16);
}
#endif

// ---------- async global->LDS, 16B per lane ----------
#if __has_builtin(__builtin_amdgcn_global_load_lds)
DEV void async16(const uint16_t* g, uint16_t* l) {
    __builtin_amdgcn_global_load_lds(
        (const __attribute__((address_space(1))) uint32_t*)g,
        (__attribute__((address_space(3))) uint32_t*)l, 16, 0, 0);
}
#else
DEV void async16(const uint16_t* g, uint16_t* l) {
    *(u16x8*)l = *(const u16x8*)g;
}
#endif

// ---------- transpose + bf16 cast: x (B,512,961) f32 -> xbt (B*992, 512) bf16 ----------
// 128n x 32c tiles (8192 blocks, was 31744 tiny ones). Loads: lane-contiguous
// scalar f32 (128B/instr per 32 lanes, full coalescing; float4 would be
// 16B-misaligned since 961 is odd). rows n in [961,992) zeroed.
__global__ void k_convert_x(const float* __restrict__ x, uint16_t* __restrict__ xbt) {
    __shared__ float tile[32][132];   // stride 132: odd-ish bank spread, 16.9 KB
    int b = blockIdx.z;
    int n0 = blockIdx.x * 128;        // 0,128,...,896
    int c0 = blockIdx.y * 32;
    int t = threadIdx.x;              // 256
    const int cl = t >> 5;            // 0..7
    const int ln = t & 31;            // 0..31
    #pragma unroll
    for (int i = 0; i < 4; ++i) {
        int c = c0 + cl + 8 * i;
        const float* xr = x + ((size_t)b * 512 + c) * 961 + n0;
        #pragma unroll
        for (int jj = 0; jj < 4; ++jj) {
            int nl = ln + 32 * jj;
            tile[cl + 8 * i][nl] = (n0 + nl < 961) ? xr[nl] : 0.f;
        }
    }
    __syncthreads();
    const int c4 = (t & 7) * 4;       // 0..28
    const int nb = t >> 3;            // 0..31
    #pragma unroll
    for (int ps = 0; ps < 4; ++ps) {
        int nl = nb + 32 * ps;
        int n = n0 + nl;
        if (n < NS) {
            ushort4 val;
            val.x = f2bf(tile[c4 + 0][nl]);
            val.y = f2bf(tile[c4 + 1][nl]);
            val.z = f2bf(tile[c4 + 2][nl]);
            val.w = f2bf(tile[c4 + 3][nl]);
            *(ushort4*)&xbt[((size_t)b * NS + n) * 512 + c0 + c4] = val;
        }
    }
}

// merged weight converts: wvkt[j][k] (1024x512 B^T) and wfct[j][k] (512x1024 B^T)
__global__ void k_convert_w(const float* __restrict__ wv, const float* __restrict__ wk,
                            const float* __restrict__ wfc,
                            uint16_t* __restrict__ wvkt, uint16_t* __restrict__ wfct) {
    int idx = blockIdx.x * 256 + threadIdx.x;   // 0 .. 1048575
    if (idx < 524288) {
        int j = idx >> 9, k = idx & 511;
        float v = (j < 512) ? wv[(size_t)k * 512 + j] : wk[(size_t)k * 512 + (j - 512)];
        wvkt[idx] = f2bf(v);
    } else {
        int t = idx - 524288;
        int j = t >> 10, k = t & 1023;
        wfct[t] = f2bf(wfc[(size_t)k * 512 + j]);
    }
}

// ---------- bf16 MFMA GEMM, 128x128 tile, BK=32 double-buffered pipeline ----------
// T3 "minimum 2-phase" schedule (r6: 104->98 µs, FETCH/WRITE at ideal).
// LDS = exactly 32 KB (sStat overlaid at sbuf+28KB, only used post-K-loop and
// disjoint from the epilogue's 0-17.4KB transpose region) -> 5 blocks/CU
// (was 4 at 34 KB): +25% wave-level TLP to hide the per-panel barrier drain.
// Stats DETERMINISTIC: unique partial slot per block, fixed-order reduce after.
// Granule swizzle (rule #21): slot (m,kq) holds global granule (m, kq^((m>>1)&3));
// read at m*32 + (quad^((m>>1)&3))*8 -> 2-way LDS aliasing (free).
template<int K, int EPI>
__global__ __launch_bounds__(256, 4)
void k_gemm(const uint16_t* __restrict__ A, const uint16_t* __restrict__ Bt,
            uint16_t* __restrict__ out_v, uint16_t* __restrict__ out_k,
            float* __restrict__ out_f,
            float* __restrict__ part)
{
    __shared__ __align__(16) uint16_t sbuf[16384];   // 32 KB total (exactly)
    uint16_t* const sA0 = sbuf;
    uint16_t* const sB0 = sbuf + 4096;
    uint16_t* const sA1 = sbuf + 8192;
    uint16_t* const sB1 = sbuf + 12288;
    float* const sStat = (float*)(sbuf + 14336);     // bytes 28672..30719 (512 f32)

    const int tid = threadIdx.x;
    const int wave = tid >> 6, lane = tid & 63;
    const int quad = lane >> 4, l16 = lane & 15;
    int m0, j0, mbi = 0;
    if constexpr (EPI == 0) {
        // XCD swizzle: same mb on same XCD for 8 consecutive rounds (A-tile L2 reuse)
        int lin = blockIdx.x;
        int xcd = lin & 7, rest = lin >> 3;
        int jb = rest & 7, mhi = rest >> 3;
        int mb = mhi * 8 + xcd;            // 0..495, grid exact (3968 blocks)
        m0 = mb * 128; j0 = jb * 128; mbi = mb;
    } else {
        m0 = blockIdx.y * 128; j0 = blockIdx.x * 128; mbi = blockIdx.y;
    }
    const int wm = wave >> 1, wj = wave & 1;

    const f32x4 fzero = {0.f, 0.f, 0.f, 0.f};
    f32x4 acc[4][4];
    #pragma unroll
    for (int i = 0; i < 4; ++i)
        #pragma unroll
        for (int j = 0; j < 4; ++j) acc[i][j] = fzero;

    const int c0 = tid;
    const int mA0 = c0 >> 2;
    const int sq0 = (c0 & 3) ^ ((mA0 >> 1) & 3);   // inverse-swizzled source granule
    const int c1 = tid + 256;
    const int mA1 = c1 >> 2;
    const int sq1 = (c1 & 3) ^ ((mA1 >> 1) & 3);

    // stage one 128x32 A-panel + B-panel (4 async16/thread) for k-panel p
    auto stage = [&](int p, uint16_t* dA, uint16_t* dB) {
        const uint16_t* Ak = A + (size_t)m0 * K + p * 32;
        const uint16_t* Bk = Bt + (size_t)j0 * K + p * 32;
        async16(Ak + (size_t)mA0 * K + sq0 * 8, &dA[c0 * 8]);
        async16(Ak + (size_t)mA1 * K + sq1 * 8, &dA[c1 * 8]);
        async16(Bk + (size_t)mA0 * K + sq0 * 8, &dB[c0 * 8]);
        async16(Bk + (size_t)mA1 * K + sq1 * 8, &dB[c1 * 8]);
    };
    auto compute = [&](const uint16_t* pA, const uint16_t* pB) {
        bf16x8 af[4], bfr[4];
        #pragma unroll
        for (int i = 0; i < 4; ++i) {
            int m = wm * 64 + i * 16 + l16;
            int qs = quad ^ ((m >> 1) & 3);
            u16x8 r = *(const u16x8*)&pA[m * 32 + qs * 8];
            af[i] = __builtin_bit_cast(bf16x8, r);
        }
        #pragma unroll
        for (int j = 0; j < 4; ++j) {
            int jj = wj * 64 + j * 16 + l16;
            int qs = quad ^ ((jj >> 1) & 3);
            u16x8 r = *(const u16x8*)&pB[jj * 32 + qs * 8];
            bfr[j] = __builtin_bit_cast(bf16x8, r);
        }
        #pragma unroll
        for (int i = 0; i < 4; ++i)
            #pragma unroll
            for (int j = 0; j < 4; ++j)
                acc[i][j] = __builtin_amdgcn_mfma_f32_16x16x32_bf16(af[i], bfr[j], acc[i][j], 0, 0, 0);
    };
    auto panel_sync = [&]() {
        asm volatile("s_waitcnt vmcnt(0)" ::: "memory");
        __builtin_amdgcn_s_barrier();
        __builtin_amdgcn_sched_barrier(0);
    };

    constexpr int NP = K / 32;   // even (16 or 32)
    stage(0, sA0, sB0);
    panel_sync();
    for (int p = 0; p < NP; p += 2) {
        stage(p + 1, sA1, sB1);          // overlaps compute of panel p
        compute(sA0, sB0);
        panel_sync();                    // drain p+1 loads (landed under compute), join waves
        if (p + 2 < NP) stage(p + 2, sA0, sB0);
        compute(sA1, sB1);
        panel_sync();
    }

    // ---- column stats: deterministic (pad rows are exactly zero -> unconditional) ----
    // sStat overlays sbuf bytes 28672+; all K-loop reads are complete (final
    // panel_sync above), so clobbering the last staging panel is safe.
    #pragma unroll
    for (int j = 0; j < 4; ++j) {
        const int col_local = wj * 64 + j * 16 + l16;
        float ls = 0.f, lq = 0.f;
        #pragma unroll
        for (int i = 0; i < 4; ++i) {
            #pragma unroll
            for (int reg = 0; reg < 4; ++reg) {
                const float val = acc[i][j][reg];
                ls += val; lq += val * val;
                if constexpr (EPI == 1) {
                    const int r = m0 + wm * 64 + i * 16 + quad * 4 + reg;
                    out_f[(size_t)r * 512 + (j0 + col_local)] = val;
                }
            }
        }
        ls += __shfl_xor(ls, 16); lq += __shfl_xor(lq, 16);
        ls += __shfl_xor(ls, 32); lq += __shfl_xor(lq, 32);
        if (quad == 0) {                      // unique writer per (wm, col_local)
            sStat[wm * 128 + col_local] = ls;
            sStat[256 + wm * 128 + col_local] = lq;
        }
    }
    __syncthreads();
    if (tid < 128) {                          // fixed-order combine wm=0 then wm=1
        float s = sStat[tid] + sStat[128 + tid];
        float q = sStat[256 + tid] + sStat[384 + tid];
        if constexpr (EPI == 0) {
            part[(size_t)mbi * 1024 + (j0 + tid)] = s;
            part[(size_t)NMB0 * 1024 + (size_t)mbi * 1024 + (j0 + tid)] = q;
        } else {
            part[(size_t)mbi * 512 + (j0 + tid)] = s;
            part[(size_t)NMB1 * 512 + (size_t)mbi * 512 + (j0 + tid)] = q;
        }
    }

    if constexpr (EPI == 0) {
        // ---- LDS transpose -> aligned 8B coalesced stores ----
        // Tile: 64 cols x 128 rows, col-major, row stride 136 ushorts
        // (bytes 0..17407 of sbuf — disjoint from sStat at 28672+).
        #pragma unroll
        for (int ch = 0; ch < 2; ++ch) {
            if (wj == ch) {
                #pragma unroll
                for (int j = 0; j < 4; ++j) {
                    const int c = j * 16 + l16;
                    #pragma unroll
                    for (int i = 0; i < 4; ++i) {
                        const int rloc = wm * 64 + i * 16 + quad * 4;
                        uint2 pp;
                        pp.x = pk2bf(acc[i][j][0], acc[i][j][1]);
                        pp.y = pk2bf(acc[i][j][2], acc[i][j][3]);
                        *(uint2*)&sbuf[c * 136 + rloc] = pp;
                    }
                }
            }
            __syncthreads();
            const int jg = j0 + ch * 64;                 // block-uniform
            uint16_t* const outp = (jg < 512) ? out_v : out_k;
            const int jbase = (jg < 512) ? jg : jg - 512;
            #pragma unroll
            for (int s = 0; s < 8; ++s) {
                const int chunk = tid + 256 * s;         // 2048 chunks
                const int c = chunk >> 5, q = chunk & 31;
                uint2 val = *(const uint2*)&sbuf[c * 136 + q * 4];
                const int r = m0 + q * 4;
                const unsigned bb_ = (unsigned)r / (unsigned)NS;
                const unsigned nn = (unsigned)r - bb_ * (unsigned)NS;  // ≡0 mod 4
                *(uint2*)&outp[((size_t)bb_ * 512 + jbase + c) * NS + nn] = val;
            }
            __syncthreads();
        }
    }
}

// ---------- deterministic stats reduction, two-stage, fixed order ----------
template<int NMB, int NC>
__global__ void k_redA(const float* __restrict__ part, float* __restrict__ pp)
{
    static_assert(NMB % RCH == 0, "exact chunks");
    int col = blockIdx.x * 256 + threadIdx.x;
    int cz = blockIdx.y;
    int i0 = cz * RCH;
    float s = 0.f, q = 0.f;
    #pragma unroll
    for (int k = 0; k < RCH; ++k) {
        int i = i0 + k;
        s += part[(size_t)i * NC + col];
        q += part[(size_t)(NMB + i) * NC + col];
    }
    constexpr int nch = NMB / RCH;
    pp[(size_t)cz * NC + col] = s;
    pp[(size_t)(nch + cz) * NC + col] = q;
}

template<int NCH, int NC>
__global__ void k_redB(const float* __restrict__ pp, float* __restrict__ osum,
                       float* __restrict__ osq)
{
    int col = blockIdx.x * 256 + threadIdx.x;
    float s = 0.f, q = 0.f;
    #pragma unroll
    for (int k = 0; k < NCH; ++k) {
        s += pp[(size_t)k * NC + col];
        q += pp[(size_t)(NCH + k) * NC + col];
    }
    osum[col] = s;
    osq[col] = q;
}

template<int NMB, int NC>
__global__ void k_redsmall(const float* __restrict__ part, float* __restrict__ osum,
                           float* __restrict__ osq)
{
    int col = blockIdx.x * 256 + threadIdx.x;
    float s = 0.f, q = 0.f;
    #pragma unroll
    for (int i = 0; i < NMB; ++i) {
        s += part[(size_t)i * NC + col];
        q += part[(size_t)(NMB + i) * NC + col];
    }
    osum[col] = s;
    osq[col] = q;
}

// ---------- attention: per (b,h) softmax over 961 + per-head window means ----------
__global__ void k_attn(const uint16_t* __restrict__ kraw,
                       const float* __restrict__ colsum, const float* __restrict__ colsq,
                       const float* __restrict__ g_kn, const float* __restrict__ b_kn,
                       float* __restrict__ attn, float* __restrict__ maw)
{
    __shared__ float qa[64];
    __shared__ float s_qb;
    __shared__ float att[NS];
    __shared__ float red[8];

    int bh = blockIdx.x;          // b*8 + h
    int b = bh >> 3, h = bh & 7;
    int tid = threadIdx.x;        // 256
    constexpr float invM = 1.f / 61504.f;

    if (tid < 64) {               // BN affine + center-pixel query
        int c = h * 64 + tid;
        float mean = colsum[512 + c] * invM;
        float q_ = colsq[512 + c] * invM;
        float a = g_kn[c] * rsqrtf(q_ - mean * mean + 1e-5f);
        float bb = b_kn[c] - mean * a;
        float kr = bf2f(kraw[((size_t)b * 512 + c) * NS + 480]);
        float qv = kr * a + bb;
        qa[tid] = qv * a;
        float qb = qv * bb;
        for (int off = 32; off; off >>= 1) qb += __shfl_down(qb, off);
        if (tid == 0) s_qb = qb;
    }
    __syncthreads();

    const int n4 = tid * 4;
    const bool active = n4 < 961;
    float a0 = 0.f, a1 = 0.f, a2 = 0.f, a3 = 0.f;
    if (active) {
        const uint16_t* kp = kraw + ((size_t)b * 512 + h * 64) * NS + n4;
        #pragma unroll 16
        for (int dd = 0; dd < 64; ++dd) {
            uint2 kk = *(const uint2*)(kp + (size_t)dd * NS);
            float q = qa[dd];
            a0 += q * bflo(kk.x);
            a1 += q * bfhi(kk.x);
            a2 += q * bflo(kk.y);
            a3 += q * bfhi(kk.y);
        }
    }
    float lg[4] = {a0, a1, a2, a3};
    float lmax = -1e30f;
    #pragma unroll
    for (int i = 0; i < 4; ++i) {
        lg[i] = (lg[i] + s_qb) * 0.125f;
        if (n4 + i < 961) lmax = fmaxf(lmax, lg[i]);
    }
    for (int off = 32; off; off >>= 1) lmax = fmaxf(lmax, __shfl_xor(lmax, off));
    if ((tid & 63) == 0) red[tid >> 6] = lmax;
    __syncthreads();
    float bmax = fmaxf(fmaxf(red[0], red[1]), fmaxf(red[2], red[3]));

    float lsum = 0.f;
    #pragma unroll
    for (int i = 0; i < 4; ++i) {
        float e = (n4 + i < 961) ? __expf(lg[i] - bmax) : 0.f;
        lg[i] = e;
        lsum += e;
    }
    for (int off = 32; off; off >>= 1) lsum += __shfl_xor(lsum, off);
    if ((tid & 63) == 0) red[4 + (tid >> 6)] = lsum;
    __syncthreads();
    float inv = 1.f / (red[4] + red[5] + red[6] + red[7]);
    if (active) {
        f32x4 v = {lg[0] * inv, lg[1] * inv, lg[2] * inv, lg[3] * inv};
        *(f32x4*)&att[n4] = v;
        *(f32x4*)&attn[(size_t)bh * NS + n4] = v;
    }
    __syncthreads();

    // 31x31 inclusive 2D prefix in LDS (serial: TLP hides it; wave-parallel
    // variant measured r5: 4x more issue work -> slower. Keep serial.)
    if (tid < 31) { float s = 0.f; for (int cc = 0; cc < 31; ++cc) { s += att[tid * 31 + cc]; att[tid * 31 + cc] = s; } }
    __syncthreads();
    if (tid < 31) { float s = 0.f; for (int rr = 0; rr < 31; ++rr) { s += att[rr * 31 + tid]; att[rr * 31 + tid] = s; } }
    __syncthreads();

    if (tid < 75) {
        int i = tid / 5 + 1, t = tid % 5;
        const int m = 15;
        int r0, r1, cc0, cc1;
        switch (t) {
            case 0: r0 = m - i; r1 = m + i + 1; cc0 = m - i; cc1 = m + i + 1; break;
            case 1: r0 = m - i; r1 = m + 1;     cc0 = m - i; cc1 = m + i + 1; break;
            case 2: r0 = m;     r1 = m + i + 1; cc0 = m - i; cc1 = m + i + 1; break;
            case 3: r0 = m - i; r1 = m + i + 1; cc0 = m - i; cc1 = m + 1;     break;
            default:r0 = m - i; r1 = m + i + 1; cc0 = m;     cc1 = m + i + 1; break;
        }
        auto S = [&](int r, int c) -> float { return (r < 0 || c < 0) ? 0.f : att[r * 31 + c]; };
        float box = S(r1 - 1, cc1 - 1) - S(r0 - 1, cc1 - 1) - S(r1 - 1, cc0 - 1) + S(r0 - 1, cc0 - 1);
        float cnt = (float)((r1 - r0) * (cc1 - cc0));
        maw[(size_t)bh * 75 + tid] = box / cnt;
    }
}

// ---------- window box means per (b,c); BN affine for v computed inline ----------
__global__ void k_winbox(const uint16_t* __restrict__ vraw,
                         const float* __restrict__ colsum, const float* __restrict__ colsq,
                         const float* __restrict__ g_vn, const float* __restrict__ b_vn,
                         const float* __restrict__ attn, const float* __restrict__ maw,
                         float* __restrict__ y)
{
    __shared__ float xw[NS];
    __shared__ float s_center;
    int bc = blockIdx.x;            // b*512 + c
    int b = bc >> 9, c = bc & 511;
    int h = c >> 6;
    int tid = threadIdx.x;          // 256
    constexpr float invM = 1.f / 61504.f;
    float mean = colsum[c] * invM;
    float q_ = colsq[c] * invM;
    float a = g_vn[c] * rsqrtf(q_ - mean * mean + 1e-5f);
    float bb = b_vn[c] - mean * a;
    const uint16_t* vp = vraw + (size_t)bc * NS;
    const float* ap = attn + (size_t)(b * 8 + h) * NS;
    int n4 = tid * 4;
    if (n4 < 961) {
        uint2 kk = *(const uint2*)(vp + n4);
        f32x4 at = *(const f32x4*)(ap + n4);
        f32x4 v;
        v[0] = fmaxf(bflo(kk.x) * a + bb, 0.f) * at[0];
        v[1] = fmaxf(bfhi(kk.x) * a + bb, 0.f) * at[1];
        v[2] = fmaxf(bflo(kk.y) * a + bb, 0.f) * at[2];
        v[3] = fmaxf(bfhi(kk.y) * a + bb, 0.f) * at[3];
        *(f32x4*)&xw[n4] = v;
    }
    __syncthreads();
    if (tid == 0) s_center = xw[480];
    __syncthreads();
    if (tid < 31) { float s = 0.f; for (int cc = 0; cc < 31; ++cc) { s += xw[tid * 31 + cc]; xw[tid * 31 + cc] = s; } }
    __syncthreads();
    if (tid < 31) { float s = 0.f; for (int rr = 0; rr < 31; ++rr) { s += xw[rr * 31 + tid]; xw[rr * 31 + tid] = s; } }
    __syncthreads();
    if (tid < 75) {
        int i = tid / 5 + 1, t = tid % 5;
        const int m = 15;
        int r0, r1, cc0, cc1;
        switch (t) {
            case 0: r0 = m - i; r1 = m + i + 1; cc0 = m - i; cc1 = m + i + 1; break;
            case 1: r0 = m - i; r1 = m + 1;     cc0 = m - i; cc1 = m + i + 1; break;
            case 2: r0 = m;     r1 = m + i + 1; cc0 = m - i; cc1 = m + i + 1; break;
            case 3: r0 = m - i; r1 = m + i + 1; cc0 = m - i; cc1 = m + 1;     break;
            default:r0 = m - i; r1 = m + i + 1; cc0 = m;     cc1 = m + i + 1; break;
        }
        auto S = [&](int r, int cc) -> float { return (r < 0 || cc < 0) ? 0.f : xw[r * 31 + cc]; };
        float box = S(r1 - 1, cc1 - 1) - S(r0 - 1, cc1 - 1) - S(r1 - 1, cc0 - 1) + S(r0 - 1, cc0 - 1);
        float cnt = (float)((r1 - r0) * (cc1 - cc0));
        float mx = box / cnt;
        float ma = maw[(size_t)(b * 8 + h) * 75 + tid];
        y[((size_t)b * 76 + 1 + tid) * 512 + c] = mx / (ma + 1e-16f);
    }
    if (tid == 96) y[((size_t)b * 76) * 512 + c] = s_center;
}

// ---------- row L2-normalize y, build yy = [x0_bf16 | bf16(y/||y||)] ----------
__global__ void k_build_yy(const float* __restrict__ y, const uint16_t* __restrict__ xbt,
                           uint16_t* __restrict__ yy)
{
    __shared__ float red[4];
    int row = blockIdx.x;           // b*76 + r
    int b = row / 76;
    int tid = threadIdx.x;          // 256
    const float* yp = y + (size_t)row * 512;
    float v0 = yp[tid], v1 = yp[tid + 256];
    float ss = v0 * v0 + v1 * v1;
    for (int off = 32; off; off >>= 1) ss += __shfl_xor(ss, off);
    if ((tid & 63) == 0) red[tid >> 6] = ss;
    __syncthreads();
    float tot = red[0] + red[1] + red[2] + red[3];
    float inv = 1.f / fmaxf(sqrtf(tot), 1e-12f);
    uint16_t* op = yy + (size_t)row * 1024;
    const uint16_t* x0p = xbt + ((size_t)b * NS + 480) * 512;
    op[tid]           = x0p[tid];
    op[tid + 256]     = x0p[tid + 256];
    op[512 + tid]       = f2bf(v0 * inv);
    op[512 + tid + 256] = f2bf(v1 * inv);
}

// ---------- final BN + relu (BN affine inline from stats) ----------
__global__ void k_fcout(const float* __restrict__ fcraw,
                        const float* __restrict__ colsum, const float* __restrict__ colsq,
                        const float* __restrict__ g, const float* __restrict__ be,
                        float* __restrict__ out)
{
    size_t idx = (size_t)blockIdx.x * 256 + threadIdx.x;
    if (idx < (size_t)4864 * 512) {
        int j = (int)(idx & 511);
        constexpr float invM = 1.f / 4864.f;
        float mean = colsum[j] * invM;
        float q_ = colsq[j] * invM;
        float a = g[j] * rsqrtf(q_ - mean * mean + 1e-5f);
        float bb = be[j] - mean * a;
        out[idx] = fmaxf(fcraw[idx] * a + bb, 0.f);
    }
}

extern "C" void kernel_launch(void* const* d_in, const int* in_sizes, int n_in,
                              void* d_out, int out_size, void* d_ws, size_t ws_size,
                              hipStream_t stream)
{
    (void)in_sizes; (void)n_in; (void)out_size; (void)ws_size;
    const float* x    = (const float*)d_in[0];
    const float* w_v  = (const float*)d_in[1];
    const float* g_vn = (const float*)d_in[3];
    const float* b_vn = (const float*)d_in[4];
    const float* w_k  = (const float*)d_in[5];
    const float* g_kn = (const float*)d_in[7];
    const float* b_kn = (const float*)d_in[8];
    const float* w_fc = (const float*)d_in[9];
    const float* g_fcn = (const float*)d_in[11];
    const float* b_fcn = (const float*)d_in[12];
    float* out = (float*)d_out;

    char* base = (char*)d_ws;
    size_t off = 0;
    auto alloc = [&](size_t bytes) -> void* {
        void* p = base + off;
        off += (bytes + 255) & ~(size_t)255;
        return p;
    };
    uint16_t* xbt  = (uint16_t*)alloc((size_t)64 * NS * 512 * 2);   // padded rows zeroed
    uint16_t* wvkt = (uint16_t*)alloc((size_t)1024 * 512 * 2);
    uint16_t* wfct = (uint16_t*)alloc((size_t)512 * 1024 * 2);
    uint16_t* vraw = (uint16_t*)alloc((size_t)64 * 512 * NS * 2);
    uint16_t* kraw = (uint16_t*)alloc((size_t)64 * 512 * NS * 2);
    float* stats   = (float*)alloc(3072 * 4);   // vk sum[1024], vk sq[1024], fc sum[512], fc sq[512]
    float* attn    = (float*)alloc((size_t)512 * NS * 4);
    float* maw     = (float*)alloc((size_t)512 * 75 * 4);
    float* y       = (float*)alloc((size_t)64 * 76 * 512 * 4);
    uint16_t* yy   = (uint16_t*)alloc((size_t)4864 * 1024 * 2);
    float* fcraw   = (float*)alloc((size_t)4864 * 512 * 4);
    float* part0   = (float*)alloc((size_t)2 * NMB0 * 1024 * 4);    // deterministic stat partials
    float* part1   = (float*)alloc((size_t)2 * NMB1 * 512 * 4);
    float* pp0     = (float*)alloc((size_t)2 * NCH0 * 1024 * 4);    // stage-A chunk partials

    k_convert_x<<<dim3(8, 16, 64), 256, 0, stream>>>(x, xbt);
    k_convert_w<<<4096, 256, 0, stream>>>(w_v, w_k, w_fc, wvkt, wfct);

    // 62*8*8 = 3968 blocks; kernel derives (m,j) with XCD-affine swizzle (496 m-tiles, exact)
    k_gemm<512, 0><<<3968, 256, 0, stream>>>(xbt, wvkt, vraw, kraw, nullptr, part0);
    k_redA<NMB0, 1024><<<dim3(4, NCH0), 256, 0, stream>>>(part0, pp0);
    k_redB<NCH0, 1024><<<4, 256, 0, stream>>>(pp0, stats, stats + 1024);

    k_attn<<<512, 256, 0, stream>>>(kraw, stats, stats + 1024, g_kn, b_kn, attn, maw);
    k_winbox<<<64 * 512, 256, 0, stream>>>(vraw, stats, stats + 1024, g_vn, b_vn, attn, maw, y);
    k_build_yy<<<4864, 256, 0, stream>>>(y, xbt, yy);

    k_gemm<1024, 1><<<dim3(4, 38), 256, 0, stream>>>(yy, wfct, nullptr, nullptr, fcraw, part1);
    k_redsmall<NMB1, 512><<<2, 256, 0, stream>>>(part1, stats + 2048, stats + 2560);
    k_fcout<<<9728, 256, 0, stream>>>(fcraw, stats + 2048, stats + 2560, g_fcn, b_fcn, out);
}

// Round 9
// 422.288 us; speedup vs baseline: 1.1154x; 1.0372x over previous
//
#include <hip/hip_runtime.h>
#include <stdint.h>

#define DEV __device__ __forceinline__

typedef __bf16 bf16x8 __attribute__((ext_vector_type(8)));
typedef unsigned short u16x8 __attribute__((ext_vector_type(8)));
typedef float f32x4 __attribute__((ext_vector_type(4)));

// n-dimension padded stride: 992 = 31*32 -> NS*2 bytes ≡ 0 mod 64 (aligned
// epilogue segments), 64*NS/128 = 496 m-tiles divisible by 8.
#define NS 992
#define NMB0 496   // m-tiles in main GEMM (deterministic stats partials)
#define NMB1 38    // m-tiles in FC GEMM
#define RCH 16     // stage-A chunk size (m-tiles per chunk)
#define NCH0 (NMB0 / RCH)   // 31 chunks, exact

// ---------- bf16 helpers (RNE) ----------
DEV uint16_t f2bf(float f) {
    union { float f; uint32_t u; } v; v.f = f;
    uint32_t r = v.u + 0x7fffu + ((v.u >> 16) & 1u);
    return (uint16_t)(r >> 16);
}
DEV float bf2f(uint16_t h) {
    union { uint32_t u; float f; } v; v.u = ((uint32_t)h) << 16;
    return v.f;
}
DEV float bflo(uint32_t w) { union { uint32_t u; float f; } v; v.u = w << 16; return v.f; }
DEV float bfhi(uint32_t w) { union { uint32_t u; float f; } v; v.u = w & 0xffff0000u; return v.f; }

#if __has_builtin(__builtin_amdgcn_cvt_pk_bf16_f32)
typedef __bf16 bf16x2 __attribute__((ext_vector_type(2)));
DEV uint32_t pk2bf(float lo, float hi) {
    bf16x2 r = __builtin_amdgcn_cvt_pk_bf16_f32(lo, hi);
    return __builtin_bit_cast(uint32_t, r);
}
#else
DEV uint32_t pk2bf(float lo, float hi) {
    return (uint32_t)f2bf(lo) | ((uint32_t)f2bf(hi) << 16);
}
#endif

// ---------- async global->LDS, 16B per lane ----------
#if __has_builtin(__builtin_amdgcn_global_load_lds)
DEV void async16(const uint16_t* g, uint16_t* l) {
    __builtin_amdgcn_global_load_lds(
        (const __attribute__((address_space(1))) uint32_t*)g,
        (__attribute__((address_space(3))) uint32_t*)l, 16, 0, 0);
}
#else
DEV void async16(const uint16_t* g, uint16_t* l) {
    *(u16x8*)l = *(const u16x8*)g;
}
#endif

// ---------- merged converts (one node) ----------
// blocks [0,8192): x (B,512,961) f32 -> xbt (B*992,512) bf16, 64c x 64n tiles.
//   Stores: 16 threads cover 64 consecutive c (128B = FULL cache line) per n
//   -> no partial-line write-allocate (old 32c tile wrote 64B half-lines).
// blocks [8192,12288): weight transposes wvkt (1024x512) / wfct (512x1024).
__global__ void k_convert(const float* __restrict__ x,
                          const float* __restrict__ wv, const float* __restrict__ wk,
                          const float* __restrict__ wfc,
                          uint16_t* __restrict__ xbt,
                          uint16_t* __restrict__ wvkt, uint16_t* __restrict__ wfct)
{
    __shared__ float tile[64][65];    // 16.6 KB; +1 pad col
    int bid = blockIdx.x;
    int t = threadIdx.x;              // 256
    if (bid < 8192) {
        int bx = bid & 15, by = (bid >> 4) & 7, b = bid >> 7;
        int n0 = bx * 64, c0 = by * 64;
        const int cl = t >> 5;        // 0..7
        const int ln = t & 31;        // 0..31
        #pragma unroll
        for (int i = 0; i < 8; ++i) {
            int c = c0 + cl + 8 * i;
            const float* xr = x + ((size_t)b * 512 + c) * 961 + n0;
            #pragma unroll
            for (int jj = 0; jj < 2; ++jj) {
                int nl = ln + 32 * jj;
                tile[cl + 8 * i][nl] = (n0 + nl < 961) ? xr[nl] : 0.f;
            }
        }
        __syncthreads();
        const int c4 = (t & 15) * 4;  // 0..60
        const int nb = t >> 4;        // 0..15
        #pragma unroll
        for (int ps = 0; ps < 4; ++ps) {
            int nl = nb + 16 * ps;
            int n = n0 + nl;
            if (n < NS) {
                ushort4 val;
                val.x = f2bf(tile[c4 + 0][nl]);
                val.y = f2bf(tile[c4 + 1][nl]);
                val.z = f2bf(tile[c4 + 2][nl]);
                val.w = f2bf(tile[c4 + 3][nl]);
                *(ushort4*)&xbt[((size_t)b * NS + n) * 512 + c0 + c4] = val;
            }
        }
    } else {
        int idx = (bid - 8192) * 256 + t;   // 0 .. 1048575
        if (idx < 524288) {
            int j = idx >> 9, k = idx & 511;
            float v = (j < 512) ? wv[(size_t)k * 512 + j] : wk[(size_t)k * 512 + (j - 512)];
            wvkt[idx] = f2bf(v);
        } else {
            int t2 = idx - 524288;
            int j = t2 >> 10, k = t2 & 1023;
            wfct[t2] = f2bf(wfc[(size_t)k * 512 + j]);
        }
    }
}

// ---------- bf16 MFMA GEMM, 128x128 tile, BK=32 double-buffered pipeline ----------
// T3 "minimum 2-phase" schedule (r6: 104->98; r8 +32KB-exact LDS: 98->92.7 µs).
// Stats DETERMINISTIC: unique partial slot per block, fixed-order reduce after.
// Granule swizzle (rule #21): slot (m,kq) holds global granule (m, kq^((m>>1)&3));
// read at m*32 + (quad^((m>>1)&3))*8 -> 2-way LDS aliasing (free).
template<int K, int EPI>
__global__ __launch_bounds__(256, 4)
void k_gemm(const uint16_t* __restrict__ A, const uint16_t* __restrict__ Bt,
            uint16_t* __restrict__ out_v, uint16_t* __restrict__ out_k,
            float* __restrict__ out_f,
            float* __restrict__ part)
{
    __shared__ __align__(16) uint16_t sbuf[16384];   // 32 KB total (exactly)
    uint16_t* const sA0 = sbuf;
    uint16_t* const sB0 = sbuf + 4096;
    uint16_t* const sA1 = sbuf + 8192;
    uint16_t* const sB1 = sbuf + 12288;
    float* const sStat = (float*)(sbuf + 14336);     // bytes 28672..30719 (512 f32)

    const int tid = threadIdx.x;
    const int wave = tid >> 6, lane = tid & 63;
    const int quad = lane >> 4, l16 = lane & 15;
    int m0, j0, mbi = 0;
    if constexpr (EPI == 0) {
        // XCD swizzle: same mb on same XCD for 8 consecutive rounds (A-tile L2 reuse)
        int lin = blockIdx.x;
        int xcd = lin & 7, rest = lin >> 3;
        int jb = rest & 7, mhi = rest >> 3;
        int mb = mhi * 8 + xcd;            // 0..495, grid exact (3968 blocks)
        m0 = mb * 128; j0 = jb * 128; mbi = mb;
    } else {
        m0 = blockIdx.y * 128; j0 = blockIdx.x * 128; mbi = blockIdx.y;
    }
    const int wm = wave >> 1, wj = wave & 1;

    const f32x4 fzero = {0.f, 0.f, 0.f, 0.f};
    f32x4 acc[4][4];
    #pragma unroll
    for (int i = 0; i < 4; ++i)
        #pragma unroll
        for (int j = 0; j < 4; ++j) acc[i][j] = fzero;

    const int c0 = tid;
    const int mA0 = c0 >> 2;
    const int sq0 = (c0 & 3) ^ ((mA0 >> 1) & 3);   // inverse-swizzled source granule
    const int c1 = tid + 256;
    const int mA1 = c1 >> 2;
    const int sq1 = (c1 & 3) ^ ((mA1 >> 1) & 3);

    // stage one 128x32 A-panel + B-panel (4 async16/thread) for k-panel p
    auto stage = [&](int p, uint16_t* dA, uint16_t* dB) {
        const uint16_t* Ak = A + (size_t)m0 * K + p * 32;
        const uint16_t* Bk = Bt + (size_t)j0 * K + p * 32;
        async16(Ak + (size_t)mA0 * K + sq0 * 8, &dA[c0 * 8]);
        async16(Ak + (size_t)mA1 * K + sq1 * 8, &dA[c1 * 8]);
        async16(Bk + (size_t)mA0 * K + sq0 * 8, &dB[c0 * 8]);
        async16(Bk + (size_t)mA1 * K + sq1 * 8, &dB[c1 * 8]);
    };
    auto compute = [&](const uint16_t* pA, const uint16_t* pB) {
        bf16x8 af[4], bfr[4];
        #pragma unroll
        for (int i = 0; i < 4; ++i) {
            int m = wm * 64 + i * 16 + l16;
            int qs = quad ^ ((m >> 1) & 3);
            u16x8 r = *(const u16x8*)&pA[m * 32 + qs * 8];
            af[i] = __builtin_bit_cast(bf16x8, r);
        }
        #pragma unroll
        for (int j = 0; j < 4; ++j) {
            int jj = wj * 64 + j * 16 + l16;
            int qs = quad ^ ((jj >> 1) & 3);
            u16x8 r = *(const u16x8*)&pB[jj * 32 + qs * 8];
            bfr[j] = __builtin_bit_cast(bf16x8, r);
        }
        #pragma unroll
        for (int i = 0; i < 4; ++i)
            #pragma unroll
            for (int j = 0; j < 4; ++j)
                acc[i][j] = __builtin_amdgcn_mfma_f32_16x16x32_bf16(af[i], bfr[j], acc[i][j], 0, 0, 0);
    };
    auto panel_sync = [&]() {
        asm volatile("s_waitcnt vmcnt(0)" ::: "memory");
        __builtin_amdgcn_s_barrier();
        __builtin_amdgcn_sched_barrier(0);
    };

    constexpr int NP = K / 32;   // even (16 or 32)
    stage(0, sA0, sB0);
    panel_sync();
    for (int p = 0; p < NP; p += 2) {
        stage(p + 1, sA1, sB1);          // overlaps compute of panel p
        compute(sA0, sB0);
        panel_sync();                    // drain p+1 loads (landed under compute), join waves
        if (p + 2 < NP) stage(p + 2, sA0, sB0);
        compute(sA1, sB1);
        panel_sync();
    }

    // ---- column stats: deterministic (pad rows are exactly zero -> unconditional) ----
    #pragma unroll
    for (int j = 0; j < 4; ++j) {
        const int col_local = wj * 64 + j * 16 + l16;
        float ls = 0.f, lq = 0.f;
        #pragma unroll
        for (int i = 0; i < 4; ++i) {
            #pragma unroll
            for (int reg = 0; reg < 4; ++reg) {
                const float val = acc[i][j][reg];
                ls += val; lq += val * val;
                if constexpr (EPI == 1) {
                    const int r = m0 + wm * 64 + i * 16 + quad * 4 + reg;
                    out_f[(size_t)r * 512 + (j0 + col_local)] = val;
                }
            }
        }
        ls += __shfl_xor(ls, 16); lq += __shfl_xor(lq, 16);
        ls += __shfl_xor(ls, 32); lq += __shfl_xor(lq, 32);
        if (quad == 0) {                      // unique writer per (wm, col_local)
            sStat[wm * 128 + col_local] = ls;
            sStat[256 + wm * 128 + col_local] = lq;
        }
    }
    __syncthreads();
    if (tid < 128) {                          // fixed-order combine wm=0 then wm=1
        float s = sStat[tid] + sStat[128 + tid];
        float q = sStat[256 + tid] + sStat[384 + tid];
        if constexpr (EPI == 0) {
            part[(size_t)mbi * 1024 + (j0 + tid)] = s;
            part[(size_t)NMB0 * 1024 + (size_t)mbi * 1024 + (j0 + tid)] = q;
        } else {
            part[(size_t)mbi * 512 + (j0 + tid)] = s;
            part[(size_t)NMB1 * 512 + (size_t)mbi * 512 + (j0 + tid)] = q;
        }
    }

    if constexpr (EPI == 0) {
        // ---- LDS transpose -> aligned 8B coalesced stores ----
        // Tile: 64 cols x 128 rows, col-major, row stride 136 ushorts
        // (bytes 0..17407 of sbuf — disjoint from sStat at 28672+).
        #pragma unroll
        for (int ch = 0; ch < 2; ++ch) {
            if (wj == ch) {
                #pragma unroll
                for (int j = 0; j < 4; ++j) {
                    const int c = j * 16 + l16;
                    #pragma unroll
                    for (int i = 0; i < 4; ++i) {
                        const int rloc = wm * 64 + i * 16 + quad * 4;
                        uint2 pp;
                        pp.x = pk2bf(acc[i][j][0], acc[i][j][1]);
                        pp.y = pk2bf(acc[i][j][2], acc[i][j][3]);
                        *(uint2*)&sbuf[c * 136 + rloc] = pp;
                    }
                }
            }
            __syncthreads();
            const int jg = j0 + ch * 64;                 // block-uniform
            uint16_t* const outp = (jg < 512) ? out_v : out_k;
            const int jbase = (jg < 512) ? jg : jg - 512;
            #pragma unroll
            for (int s = 0; s < 8; ++s) {
                const int chunk = tid + 256 * s;         // 2048 chunks
                const int c = chunk >> 5, q = chunk & 31;
                uint2 val = *(const uint2*)&sbuf[c * 136 + q * 4];
                const int r = m0 + q * 4;
                const unsigned bb_ = (unsigned)r / (unsigned)NS;
                const unsigned nn = (unsigned)r - bb_ * (unsigned)NS;  // ≡0 mod 4
                *(uint2*)&outp[((size_t)bb_ * 512 + jbase + c) * NS + nn] = val;
            }
            __syncthreads();
        }
    }
}

// ---------- deterministic stats reduction, stage A only (chunks of RCH) ----------
// Consumers (k_attn / k_winbox) sum the NCH0 chunk partials in the same fixed
// order -> bit-identical affine everywhere, and the redB node disappears.
template<int NMB, int NC>
__global__ void k_redA(const float* __restrict__ part, float* __restrict__ pp)
{
    static_assert(NMB % RCH == 0, "exact chunks");
    int col = blockIdx.x * 256 + threadIdx.x;
    int cz = blockIdx.y;
    int i0 = cz * RCH;
    float s = 0.f, q = 0.f;
    #pragma unroll
    for (int k = 0; k < RCH; ++k) {
        int i = i0 + k;
        s += part[(size_t)i * NC + col];
        q += part[(size_t)(NMB + i) * NC + col];
    }
    constexpr int nch = NMB / RCH;
    pp[(size_t)cz * NC + col] = s;
    pp[(size_t)(nch + cz) * NC + col] = q;
}

// Small single-stage reduce (FC stats): loop fully unrolled -> loads batched.
template<int NMB, int NC>
__global__ void k_redsmall(const float* __restrict__ part, float* __restrict__ osum,
                           float* __restrict__ osq)
{
    int col = blockIdx.x * 256 + threadIdx.x;
    float s = 0.f, q = 0.f;
    #pragma unroll
    for (int i = 0; i < NMB; ++i) {
        s += part[(size_t)i * NC + col];
        q += part[(size_t)(NMB + i) * NC + col];
    }
    osum[col] = s;
    osq[col] = q;
}

// fixed-order column stat from chunk partials (bit-identical to old redB+load)
DEV void chunk_stats(const float* __restrict__ pp, int col, float& s, float& q) {
    s = 0.f; q = 0.f;
    #pragma unroll
    for (int k = 0; k < NCH0; ++k) {
        s += pp[(size_t)k * 1024 + col];
        q += pp[(size_t)(NCH0 + k) * 1024 + col];
    }
}

// ---------- attention: per (b,h) softmax over 961 + per-head window means ----------
__global__ void k_attn(const uint16_t* __restrict__ kraw,
                       const float* __restrict__ pp0,
                       const float* __restrict__ g_kn, const float* __restrict__ b_kn,
                       float* __restrict__ attn, float* __restrict__ maw)
{
    __shared__ float qa[64];
    __shared__ float s_qb;
    __shared__ float att[NS];
    __shared__ float red[8];

    int bh = blockIdx.x;          // b*8 + h
    int b = bh >> 3, h = bh & 7;
    int tid = threadIdx.x;        // 256
    constexpr float invM = 1.f / 61504.f;

    if (tid < 64) {               // BN affine + center-pixel query
        int c = h * 64 + tid;
        float cs, cq;
        chunk_stats(pp0, 512 + c, cs, cq);
        float mean = cs * invM;
        float q_ = cq * invM;
        float a = g_kn[c] * rsqrtf(q_ - mean * mean + 1e-5f);
        float bb = b_kn[c] - mean * a;
        float kr = bf2f(kraw[((size_t)b * 512 + c) * NS + 480]);
        float qv = kr * a + bb;
        qa[tid] = qv * a;
        float qb = qv * bb;
        for (int off = 32; off; off >>= 1) qb += __shfl_down(qb, off);
        if (tid == 0) s_qb = qb;
    }
    __syncthreads();

    const int n4 = tid * 4;
    const bool active = n4 < 961;
    float a0 = 0.f, a1 = 0.f, a2 = 0.f, a3 = 0.f;
    if (active) {
        const uint16_t* kp = kraw + ((size_t)b * 512 + h * 64) * NS + n4;
        #pragma unroll 16
        for (int dd = 0; dd < 64; ++dd) {
            uint2 kk = *(const uint2*)(kp + (size_t)dd * NS);
            float q = qa[dd];
            a0 += q * bflo(kk.x);
            a1 += q * bfhi(kk.x);
            a2 += q * bflo(kk.y);
            a3 += q * bfhi(kk.y);
        }
    }
    float lg[4] = {a0, a1, a2, a3};
    float lmax = -1e30f;
    #pragma unroll
    for (int i = 0; i < 4; ++i) {
        lg[i] = (lg[i] + s_qb) * 0.125f;
        if (n4 + i < 961) lmax = fmaxf(lmax, lg[i]);
    }
    for (int off = 32; off; off >>= 1) lmax = fmaxf(lmax, __shfl_xor(lmax, off));
    if ((tid & 63) == 0) red[tid >> 6] = lmax;
    __syncthreads();
    float bmax = fmaxf(fmaxf(red[0], red[1]), fmaxf(red[2], red[3]));

    float lsum = 0.f;
    #pragma unroll
    for (int i = 0; i < 4; ++i) {
        float e = (n4 + i < 961) ? __expf(lg[i] - bmax) : 0.f;
        lg[i] = e;
        lsum += e;
    }
    for (int off = 32; off; off >>= 1) lsum += __shfl_xor(lsum, off);
    if ((tid & 63) == 0) red[4 + (tid >> 6)] = lsum;
    __syncthreads();
    float inv = 1.f / (red[4] + red[5] + red[6] + red[7]);
    if (active) {
        f32x4 v = {lg[0] * inv, lg[1] * inv, lg[2] * inv, lg[3] * inv};
        *(f32x4*)&att[n4] = v;
        *(f32x4*)&attn[(size_t)bh * NS + n4] = v;
    }
    __syncthreads();

    // 31x31 inclusive 2D prefix in LDS (serial: TLP hides it; wave-parallel
    // variant measured r5: 4x more issue work -> slower. Keep serial.)
    if (tid < 31) { float s = 0.f; for (int cc = 0; cc < 31; ++cc) { s += att[tid * 31 + cc]; att[tid * 31 + cc] = s; } }
    __syncthreads();
    if (tid < 31) { float s = 0.f; for (int rr = 0; rr < 31; ++rr) { s += att[rr * 31 + tid]; att[rr * 31 + tid] = s; } }
    __syncthreads();

    if (tid < 75) {
        int i = tid / 5 + 1, t = tid % 5;
        const int m = 15;
        int r0, r1, cc0, cc1;
        switch (t) {
            case 0: r0 = m - i; r1 = m + i + 1; cc0 = m - i; cc1 = m + i + 1; break;
            case 1: r0 = m - i; r1 = m + 1;     cc0 = m - i; cc1 = m + i + 1; break;
            case 2: r0 = m;     r1 = m + i + 1; cc0 = m - i; cc1 = m + i + 1; break;
            case 3: r0 = m - i; r1 = m + i + 1; cc0 = m - i; cc1 = m + 1;     break;
            default:r0 = m - i; r1 = m + i + 1; cc0 = m;     cc1 = m + i + 1; break;
        }
        auto S = [&](int r, int c) -> float { return (r < 0 || c < 0) ? 0.f : att[r * 31 + c]; };
        float box = S(r1 - 1, cc1 - 1) - S(r0 - 1, cc1 - 1) - S(r1 - 1, cc0 - 1) + S(r0 - 1, cc0 - 1);
        float cnt = (float)((r1 - r0) * (cc1 - cc0));
        maw[(size_t)bh * 75 + tid] = box / cnt;
    }
}

// ---------- window box means per (b,c); BN affine from chunk partials ----------
__global__ void k_winbox(const uint16_t* __restrict__ vraw,
                         const float* __restrict__ pp0,
                         const float* __restrict__ g_vn, const float* __restrict__ b_vn,
                         const float* __restrict__ attn, const float* __restrict__ maw,
                         float* __restrict__ y)
{
    __shared__ float xw[NS];
    __shared__ float s_center;
    int bc = blockIdx.x;            // b*512 + c
    int b = bc >> 9, c = bc & 511;
    int h = c >> 6;
    int tid = threadIdx.x;          // 256
    constexpr float invM = 1.f / 61504.f;
    float cs, cq;
    chunk_stats(pp0, c, cs, cq);    // block-uniform broadcast loads
    float mean = cs * invM;
    float q_ = cq * invM;
    float a = g_vn[c] * rsqrtf(q_ - mean * mean + 1e-5f);
    float bb = b_vn[c] - mean * a;
    const uint16_t* vp = vraw + (size_t)bc * NS;
    const float* ap = attn + (size_t)(b * 8 + h) * NS;
    int n4 = tid * 4;
    if (n4 < 961) {
        uint2 kk = *(const uint2*)(vp + n4);
        f32x4 at = *(const f32x4*)(ap + n4);
        f32x4 v;
        v[0] = fmaxf(bflo(kk.x) * a + bb, 0.f) * at[0];
        v[1] = fmaxf(bfhi(kk.x) * a + bb, 0.f) * at[1];
        v[2] = fmaxf(bflo(kk.y) * a + bb, 0.f) * at[2];
        v[3] = fmaxf(bfhi(kk.y) * a + bb, 0.f) * at[3];
        *(f32x4*)&xw[n4] = v;
    }
    __syncthreads();
    if (tid == 0) s_center = xw[480];
    __syncthreads();
    if (tid < 31) { float s = 0.f; for (int cc = 0; cc < 31; ++cc) { s += xw[tid * 31 + cc]; xw[tid * 31 + cc] = s; } }
    __syncthreads();
    if (tid < 31) { float s = 0.f; for (int rr = 0; rr < 31; ++rr) { s += xw[rr * 31 + tid]; xw[rr * 31 + tid] = s; } }
    __syncthreads();
    if (tid < 75) {
        int i = tid / 5 + 1, t = tid % 5;
        const int m = 15;
        int r0, r1, cc0, cc1;
        switch (t) {
            case 0: r0 = m - i; r1 = m + i + 1; cc0 = m - i; cc1 = m + i + 1; break;
            case 1: r0 = m - i; r1 = m + 1;     cc0 = m - i; cc1 = m + i + 1; break;
            case 2: r0 = m;     r1 = m + i + 1; cc0 = m - i; cc1 = m + i + 1; break;
            case 3: r0 = m - i; r1 = m + i + 1; cc0 = m - i; cc1 = m + 1;     break;
            default:r0 = m - i; r1 = m + i + 1; cc0 = m;     cc1 = m + i + 1; break;
        }
        auto S = [&](int r, int cc) -> float { return (r < 0 || cc < 0) ? 0.f : xw[r * 31 + cc]; };
        float box = S(r1 - 1, cc1 - 1) - S(r0 - 1, cc1 - 1) - S(r1 - 1, cc0 - 1) + S(r0 - 1, cc0 - 1);
        float cnt = (float)((r1 - r0) * (cc1 - cc0));
        float mx = box / cnt;
        float ma = maw[(size_t)(b * 8 + h) * 75 + tid];
        y[((size_t)b * 76 + 1 + tid) * 512 + c] = mx / (ma + 1e-16f);
    }
    if (tid == 96) y[((size_t)b * 76) * 512 + c] = s_center;
}

// ---------- row L2-normalize y, build yy = [x0_bf16 | bf16(y/||y||)] ----------
__global__ void k_build_yy(const float* __restrict__ y, const uint16_t* __restrict__ xbt,
                           uint16_t* __restrict__ yy)
{
    __shared__ float red[4];
    int row = blockIdx.x;           // b*76 + r
    int b = row / 76;
    int tid = threadIdx.x;          // 256
    const float* yp = y + (size_t)row * 512;
    float v0 = yp[tid], v1 = yp[tid + 256];
    float ss = v0 * v0 + v1 * v1;
    for (int off = 32; off; off >>= 1) ss += __shfl_xor(ss, off);
    if ((tid & 63) == 0) red[tid >> 6] = ss;
    __syncthreads();
    float tot = red[0] + red[1] + red[2] + red[3];
    float inv = 1.f / fmaxf(sqrtf(tot), 1e-12f);
    uint16_t* op = yy + (size_t)row * 1024;
    const uint16_t* x0p = xbt + ((size_t)b * NS + 480) * 512;
    op[tid]           = x0p[tid];
    op[tid + 256]     = x0p[tid + 256];
    op[512 + tid]       = f2bf(v0 * inv);
    op[512 + tid + 256] = f2bf(v1 * inv);
}

// ---------- final BN + relu (BN affine inline from stats) ----------
__global__ void k_fcout(const float* __restrict__ fcraw,
                        const float* __restrict__ colsum, const float* __restrict__ colsq,
                        const float* __restrict__ g, const float* __restrict__ be,
                        float* __restrict__ out)
{
    size_t idx = (size_t)blockIdx.x * 256 + threadIdx.x;
    if (idx < (size_t)4864 * 512) {
        int j = (int)(idx & 511);
        constexpr float invM = 1.f / 4864.f;
        float mean = colsum[j] * invM;
        float q_ = colsq[j] * invM;
        float a = g[j] * rsqrtf(q_ - mean * mean + 1e-5f);
        float bb = be[j] - mean * a;
        out[idx] = fmaxf(fcraw[idx] * a + bb, 0.f);
    }
}

extern "C" void kernel_launch(void* const* d_in, const int* in_sizes, int n_in,
                              void* d_out, int out_size, void* d_ws, size_t ws_size,
                              hipStream_t stream)
{
    (void)in_sizes; (void)n_in; (void)out_size; (void)ws_size;
    const float* x    = (const float*)d_in[0];
    const float* w_v  = (const float*)d_in[1];
    const float* g_vn = (const float*)d_in[3];
    const float* b_vn = (const float*)d_in[4];
    const float* w_k  = (const float*)d_in[5];
    const float* g_kn = (const float*)d_in[7];
    const float* b_kn = (const float*)d_in[8];
    const float* w_fc = (const float*)d_in[9];
    const float* g_fcn = (const float*)d_in[11];
    const float* b_fcn = (const float*)d_in[12];
    float* out = (float*)d_out;

    char* base = (char*)d_ws;
    size_t off = 0;
    auto alloc = [&](size_t bytes) -> void* {
        void* p = base + off;
        off += (bytes + 255) & ~(size_t)255;
        return p;
    };
    uint16_t* xbt  = (uint16_t*)alloc((size_t)64 * NS * 512 * 2);   // padded rows zeroed
    uint16_t* wvkt = (uint16_t*)alloc((size_t)1024 * 512 * 2);
    uint16_t* wfct = (uint16_t*)alloc((size_t)512 * 1024 * 2);
    uint16_t* vraw = (uint16_t*)alloc((size_t)64 * 512 * NS * 2);
    uint16_t* kraw = (uint16_t*)alloc((size_t)64 * 512 * NS * 2);
    float* stats   = (float*)alloc(3072 * 4);   // fc sum[512] @2048, fc sq[512] @2560
    float* attn    = (float*)alloc((size_t)512 * NS * 4);
    float* maw     = (float*)alloc((size_t)512 * 75 * 4);
    float* y       = (float*)alloc((size_t)64 * 76 * 512 * 4);
    uint16_t* yy   = (uint16_t*)alloc((size_t)4864 * 1024 * 2);
    float* fcraw   = (float*)alloc((size_t)4864 * 512 * 4);
    float* part0   = (float*)alloc((size_t)2 * NMB0 * 1024 * 4);    // deterministic stat partials
    float* part1   = (float*)alloc((size_t)2 * NMB1 * 512 * 4);
    float* pp0     = (float*)alloc((size_t)2 * NCH0 * 1024 * 4);    // stage-A chunk partials

    k_convert<<<12288, 256, 0, stream>>>(x, w_v, w_k, w_fc, xbt, wvkt, wfct);

    // 62*8*8 = 3968 blocks; kernel derives (m,j) with XCD-affine swizzle (496 m-tiles, exact)
    k_gemm<512, 0><<<3968, 256, 0, stream>>>(xbt, wvkt, vraw, kraw, nullptr, part0);
    k_redA<NMB0, 1024><<<dim3(4, NCH0), 256, 0, stream>>>(part0, pp0);

    k_attn<<<512, 256, 0, stream>>>(kraw, pp0, g_kn, b_kn, attn, maw);
    k_winbox<<<64 * 512, 256, 0, stream>>>(vraw, pp0, g_vn, b_vn, attn, maw, y);
    k_build_yy<<<4864, 256, 0, stream>>>(y, xbt, yy);

    k_gemm<1024, 1><<<dim3(4, 38), 256, 0, stream>>>(yy, wfct, nullptr, nullptr, fcraw, part1);
    k_redsmall<NMB1, 512><<<2, 256, 0, stream>>>(part1, stats + 2048, stats + 2560);
    k_fcout<<<9728, 256, 0, stream>>>(fcraw, stats + 2048, stats + 2560, g_fcn, b_fcn, out);
}

// Round 10
// 418.306 us; speedup vs baseline: 1.1261x; 1.0095x over previous
//
#include <hip/hip_runtime.h>
#include <stdint.h>

#define DEV __device__ __forceinline__

typedef __bf16 bf16x8 __attribute__((ext_vector_type(8)));
typedef unsigned short u16x8 __attribute__((ext_vector_type(8)));
typedef float f32x4 __attribute__((ext_vector_type(4)));

// n-dimension padded stride: 992 = 31*32 -> NS*2 bytes ≡ 0 mod 64 (aligned
// epilogue segments), 64*NS/128 = 496 m-tiles divisible by 8.
#define NS 992
#define NMB0 496   // m-tiles in main GEMM (deterministic stats partials)
#define NMB1 38    // m-tiles in FC GEMM
#define RCH 16     // stage-A chunk size (m-tiles per chunk)
#define NCH0 (NMB0 / RCH)   // 31 chunks, exact

// ---------- bf16 helpers (RNE) ----------
DEV uint16_t f2bf(float f) {
    union { float f; uint32_t u; } v; v.f = f;
    uint32_t r = v.u + 0x7fffu + ((v.u >> 16) & 1u);
    return (uint16_t)(r >> 16);
}
DEV float bf2f(uint16_t h) {
    union { uint32_t u; float f; } v; v.u = ((uint32_t)h) << 16;
    return v.f;
}
DEV float bflo(uint32_t w) { union { uint32_t u; float f; } v; v.u = w << 16; return v.f; }
DEV float bfhi(uint32_t w) { union { uint32_t u; float f; } v; v.u = w & 0xffff0000u; return v.f; }

#if __has_builtin(__builtin_amdgcn_cvt_pk_bf16_f32)
typedef __bf16 bf16x2 __attribute__((ext_vector_type(2)));
DEV uint32_t pk2bf(float lo, float hi) {
    bf16x2 r = __builtin_amdgcn_cvt_pk_bf16_f32(lo, hi);
    return __builtin_bit_cast(uint32_t, r);
}
#else
DEV uint32_t pk2bf(float lo, float hi) {
    return (uint32_t)f2bf(lo) | ((uint32_t)f2bf(hi) << 16);
}
#endif

// ---------- async global->LDS, 16B per lane ----------
#if __has_builtin(__builtin_amdgcn_global_load_lds)
DEV void async16(const uint16_t* g, uint16_t* l) {
    __builtin_amdgcn_global_load_lds(
        (const __attribute__((address_space(1))) uint32_t*)g,
        (__attribute__((address_space(3))) uint32_t*)l, 16, 0, 0);
}
#else
DEV void async16(const uint16_t* g, uint16_t* l) {
    *(u16x8*)l = *(const u16x8*)g;
}
#endif

// ---------- merged converts (one node) ----------
// blocks [0,8192): x (B,512,961) f32 -> xbt (B*992,512) bf16, 64c x 64n tiles.
//   Stores: 16 threads cover 64 consecutive c (128B = FULL cache line) per n
//   -> no partial-line write-allocate.
// blocks [8192,12288): weight transposes wvkt (1024x512) / wfct (512x1024).
__global__ void k_convert(const float* __restrict__ x,
                          const float* __restrict__ wv, const float* __restrict__ wk,
                          const float* __restrict__ wfc,
                          uint16_t* __restrict__ xbt,
                          uint16_t* __restrict__ wvkt, uint16_t* __restrict__ wfct)
{
    __shared__ float tile[64][65];    // 16.6 KB; +1 pad col
    int bid = blockIdx.x;
    int t = threadIdx.x;              // 256
    if (bid < 8192) {
        int bx = bid & 15, by = (bid >> 4) & 7, b = bid >> 7;
        int n0 = bx * 64, c0 = by * 64;
        const int cl = t >> 5;        // 0..7
        const int ln = t & 31;        // 0..31
        #pragma unroll
        for (int i = 0; i < 8; ++i) {
            int c = c0 + cl + 8 * i;
            const float* xr = x + ((size_t)b * 512 + c) * 961 + n0;
            #pragma unroll
            for (int jj = 0; jj < 2; ++jj) {
                int nl = ln + 32 * jj;
                tile[cl + 8 * i][nl] = (n0 + nl < 961) ? xr[nl] : 0.f;
            }
        }
        __syncthreads();
        const int c4 = (t & 15) * 4;  // 0..60
        const int nb = t >> 4;        // 0..15
        #pragma unroll
        for (int ps = 0; ps < 4; ++ps) {
            int nl = nb + 16 * ps;
            int n = n0 + nl;
            if (n < NS) {
                ushort4 val;
                val.x = f2bf(tile[c4 + 0][nl]);
                val.y = f2bf(tile[c4 + 1][nl]);
                val.z = f2bf(tile[c4 + 2][nl]);
                val.w = f2bf(tile[c4 + 3][nl]);
                *(ushort4*)&xbt[((size_t)b * NS + n) * 512 + c0 + c4] = val;
            }
        }
    } else {
        int idx = (bid - 8192) * 256 + t;   // 0 .. 1048575
        if (idx < 524288) {
            int j = idx >> 9, k = idx & 511;
            float v = (j < 512) ? wv[(size_t)k * 512 + j] : wk[(size_t)k * 512 + (j - 512)];
            wvkt[idx] = f2bf(v);
        } else {
            int t2 = idx - 524288;
            int j = t2 >> 10, k = t2 & 1023;
            wfct[t2] = f2bf(wfc[(size_t)k * 512 + j]);
        }
    }
}

// ---------- bf16 MFMA GEMM, 128x128 tile, BK=32, 3-buffer depth-2 pipeline ----------
// T4 counted-vmcnt schedule: stage(p+2) issues during compute(p); end-of-iter
// wait is vmcnt(4) (stage(p+2)'s 4 loads stay in flight; in-order completion
// guarantees stage(p+1) landed — m135 semantics). Never drains to 0 mid-loop.
// Each stage has ~2 panels of compute to hide its HBM/L2 latency (2-buffer
// version exposed ~500cy/panel: r8/r9 measured 93 µs vs 33 µs MFMA floor).
// LDS 48 KB (3 x 16 KB panels); sStat overlaid at byte 45056 (epilogue
// transpose uses only 0..17.4 KB). Stats DETERMINISTIC (unique slot + fixed-
// order reduce). Granule swizzle (rule #21) unchanged: 2-way LDS aliasing.
template<int K, int EPI>
__global__ __launch_bounds__(256, 3)
void k_gemm(const uint16_t* __restrict__ A, const uint16_t* __restrict__ Bt,
            uint16_t* __restrict__ out_v, uint16_t* __restrict__ out_k,
            float* __restrict__ out_f,
            float* __restrict__ part)
{
    __shared__ __align__(16) uint16_t sbuf[24576];   // 48 KB: 3 x (A 8KB + B 8KB)
    float* const sStat = (float*)(sbuf + 22528);     // bytes 45056..47103 (512 f32)

    const int tid = threadIdx.x;
    const int wave = tid >> 6, lane = tid & 63;
    const int quad = lane >> 4, l16 = lane & 15;
    int m0, j0, mbi = 0;
    if constexpr (EPI == 0) {
        // XCD swizzle: same mb on same XCD for 8 consecutive rounds (A-tile L2 reuse)
        int lin = blockIdx.x;
        int xcd = lin & 7, rest = lin >> 3;
        int jb = rest & 7, mhi = rest >> 3;
        int mb = mhi * 8 + xcd;            // 0..495, grid exact (3968 blocks)
        m0 = mb * 128; j0 = jb * 128; mbi = mb;
    } else {
        m0 = blockIdx.y * 128; j0 = blockIdx.x * 128; mbi = blockIdx.y;
    }
    const int wm = wave >> 1, wj = wave & 1;

    const f32x4 fzero = {0.f, 0.f, 0.f, 0.f};
    f32x4 acc[4][4];
    #pragma unroll
    for (int i = 0; i < 4; ++i)
        #pragma unroll
        for (int j = 0; j < 4; ++j) acc[i][j] = fzero;

    const int c0 = tid;
    const int mA0 = c0 >> 2;
    const int sq0 = (c0 & 3) ^ ((mA0 >> 1) & 3);   // inverse-swizzled source granule
    const int c1 = tid + 256;
    const int mA1 = c1 >> 2;
    const int sq1 = (c1 & 3) ^ ((mA1 >> 1) & 3);

    auto bufA = [&](int p) { return sbuf + (p % 3) * 8192; };
    auto bufB = [&](int p) { return sbuf + (p % 3) * 8192 + 4096; };

    // stage one 128x32 A-panel + B-panel (4 async16/thread) for k-panel p
    auto stage = [&](int p) {
        uint16_t* dA = bufA(p);
        uint16_t* dB = bufB(p);
        const uint16_t* Ak = A + (size_t)m0 * K + p * 32;
        const uint16_t* Bk = Bt + (size_t)j0 * K + p * 32;
        async16(Ak + (size_t)mA0 * K + sq0 * 8, &dA[c0 * 8]);
        async16(Ak + (size_t)mA1 * K + sq1 * 8, &dA[c1 * 8]);
        async16(Bk + (size_t)mA0 * K + sq0 * 8, &dB[c0 * 8]);
        async16(Bk + (size_t)mA1 * K + sq1 * 8, &dB[c1 * 8]);
    };
    auto compute = [&](int p) {
        const uint16_t* pA = bufA(p);
        const uint16_t* pB = bufB(p);
        bf16x8 af[4], bfr[4];
        #pragma unroll
        for (int i = 0; i < 4; ++i) {
            int m = wm * 64 + i * 16 + l16;
            int qs = quad ^ ((m >> 1) & 3);
            u16x8 r = *(const u16x8*)&pA[m * 32 + qs * 8];
            af[i] = __builtin_bit_cast(bf16x8, r);
        }
        #pragma unroll
        for (int j = 0; j < 4; ++j) {
            int jj = wj * 64 + j * 16 + l16;
            int qs = quad ^ ((jj >> 1) & 3);
            u16x8 r = *(const u16x8*)&pB[jj * 32 + qs * 8];
            bfr[j] = __builtin_bit_cast(bf16x8, r);
        }
        #pragma unroll
        for (int i = 0; i < 4; ++i)
            #pragma unroll
            for (int j = 0; j < 4; ++j)
                acc[i][j] = __builtin_amdgcn_mfma_f32_16x16x32_bf16(af[i], bfr[j], acc[i][j], 0, 0, 0);
    };

    constexpr int NP = K / 32;   // 16 or 32
    stage(0);
    stage(1);
    asm volatile("s_waitcnt vmcnt(4)" ::: "memory");   // panel 0 landed (panel 1 in flight)
    __builtin_amdgcn_s_barrier();
    __builtin_amdgcn_sched_barrier(0);
    for (int p = 0; p < NP; ++p) {
        if (p + 2 < NP) stage(p + 2);       // overlaps compute(p), 2 panels ahead
        compute(p);
        if (p + 2 < NP) asm volatile("s_waitcnt vmcnt(4)" ::: "memory");  // p+1 landed, p+2 in flight
        else            asm volatile("s_waitcnt vmcnt(0)" ::: "memory");  // tail drain
        __builtin_amdgcn_s_barrier();
        __builtin_amdgcn_sched_barrier(0);
    }

    // ---- column stats: deterministic (pad rows are exactly zero -> unconditional) ----
    // sStat overlays sbuf bytes 45056+; all K-loop LDS reads completed before the
    // loop's final vmcnt(0)+barrier, so clobbering staging space is safe.
    #pragma unroll
    for (int j = 0; j < 4; ++j) {
        const int col_local = wj * 64 + j * 16 + l16;
        float ls = 0.f, lq = 0.f;
        #pragma unroll
        for (int i = 0; i < 4; ++i) {
            #pragma unroll
            for (int reg = 0; reg < 4; ++reg) {
                const float val = acc[i][j][reg];
                ls += val; lq += val * val;
                if constexpr (EPI == 1) {
                    const int r = m0 + wm * 64 + i * 16 + quad * 4 + reg;
                    out_f[(size_t)r * 512 + (j0 + col_local)] = val;
                }
            }
        }
        ls += __shfl_xor(ls, 16); lq += __shfl_xor(lq, 16);
        ls += __shfl_xor(ls, 32); lq += __shfl_xor(lq, 32);
        if (quad == 0) {                      // unique writer per (wm, col_local)
            sStat[wm * 128 + col_local] = ls;
            sStat[256 + wm * 128 + col_local] = lq;
        }
    }
    __syncthreads();
    if (tid < 128) {                          // fixed-order combine wm=0 then wm=1
        float s = sStat[tid] + sStat[128 + tid];
        float q = sStat[256 + tid] + sStat[384 + tid];
        if constexpr (EPI == 0) {
            part[(size_t)mbi * 1024 + (j0 + tid)] = s;
            part[(size_t)NMB0 * 1024 + (size_t)mbi * 1024 + (j0 + tid)] = q;
        } else {
            part[(size_t)mbi * 512 + (j0 + tid)] = s;
            part[(size_t)NMB1 * 512 + (size_t)mbi * 512 + (j0 + tid)] = q;
        }
    }

    if constexpr (EPI == 0) {
        // ---- LDS transpose -> aligned 8B coalesced stores ----
        // Tile: 64 cols x 128 rows, col-major, row stride 136 ushorts
        // (bytes 0..17407 of sbuf — disjoint from sStat at 45056+).
        #pragma unroll
        for (int ch = 0; ch < 2; ++ch) {
            if (wj == ch) {
                #pragma unroll
                for (int j = 0; j < 4; ++j) {
                    const int c = j * 16 + l16;
                    #pragma unroll
                    for (int i = 0; i < 4; ++i) {
                        const int rloc = wm * 64 + i * 16 + quad * 4;
                        uint2 pp;
                        pp.x = pk2bf(acc[i][j][0], acc[i][j][1]);
                        pp.y = pk2bf(acc[i][j][2], acc[i][j][3]);
                        *(uint2*)&sbuf[c * 136 + rloc] = pp;
                    }
                }
            }
            __syncthreads();
            const int jg = j0 + ch * 64;                 // block-uniform
            uint16_t* const outp = (jg < 512) ? out_v : out_k;
            const int jbase = (jg < 512) ? jg : jg - 512;
            #pragma unroll
            for (int s = 0; s < 8; ++s) {
                const int chunk = tid + 256 * s;         // 2048 chunks
                const int c = chunk >> 5, q = chunk & 31;
                uint2 val = *(const uint2*)&sbuf[c * 136 + q * 4];
                const int r = m0 + q * 4;
                const unsigned bb_ = (unsigned)r / (unsigned)NS;
                const unsigned nn = (unsigned)r - bb_ * (unsigned)NS;  // ≡0 mod 4
                *(uint2*)&outp[((size_t)bb_ * 512 + jbase + c) * NS + nn] = val;
            }
            __syncthreads();
        }
    }
}

// ---------- deterministic stats reduction, stage A only (chunks of RCH) ----------
// Consumers (k_attn / k_winbox) sum the NCH0 chunk partials in the same fixed
// order -> bit-identical affine everywhere.
template<int NMB, int NC>
__global__ void k_redA(const float* __restrict__ part, float* __restrict__ pp)
{
    static_assert(NMB % RCH == 0, "exact chunks");
    int col = blockIdx.x * 256 + threadIdx.x;
    int cz = blockIdx.y;
    int i0 = cz * RCH;
    float s = 0.f, q = 0.f;
    #pragma unroll
    for (int k = 0; k < RCH; ++k) {
        int i = i0 + k;
        s += part[(size_t)i * NC + col];
        q += part[(size_t)(NMB + i) * NC + col];
    }
    constexpr int nch = NMB / RCH;
    pp[(size_t)cz * NC + col] = s;
    pp[(size_t)(nch + cz) * NC + col] = q;
}

// Small single-stage reduce (FC stats): loop fully unrolled -> loads batched.
template<int NMB, int NC>
__global__ void k_redsmall(const float* __restrict__ part, float* __restrict__ osum,
                           float* __restrict__ osq)
{
    int col = blockIdx.x * 256 + threadIdx.x;
    float s = 0.f, q = 0.f;
    #pragma unroll
    for (int i = 0; i < NMB; ++i) {
        s += part[(size_t)i * NC + col];
        q += part[(size_t)(NMB + i) * NC + col];
    }
    osum[col] = s;
    osq[col] = q;
}

// fixed-order column stat from chunk partials (bit-identical to old redB+load)
DEV void chunk_stats(const float* __restrict__ pp, int col, float& s, float& q) {
    s = 0.f; q = 0.f;
    #pragma unroll
    for (int k = 0; k < NCH0; ++k) {
        s += pp[(size_t)k * 1024 + col];
        q += pp[(size_t)(NCH0 + k) * 1024 + col];
    }
}

// ---------- attention: per (b,h) softmax over 961 + per-head window means ----------
__global__ void k_attn(const uint16_t* __restrict__ kraw,
                       const float* __restrict__ pp0,
                       const float* __restrict__ g_kn, const float* __restrict__ b_kn,
                       float* __restrict__ attn, float* __restrict__ maw)
{
    __shared__ float qa[64];
    __shared__ float s_qb;
    __shared__ float att[NS];
    __shared__ float red[8];

    int bh = blockIdx.x;          // b*8 + h
    int b = bh >> 3, h = bh & 7;
    int tid = threadIdx.x;        // 256
    constexpr float invM = 1.f / 61504.f;

    if (tid < 64) {               // BN affine + center-pixel query
        int c = h * 64 + tid;
        float cs, cq;
        chunk_stats(pp0, 512 + c, cs, cq);
        float mean = cs * invM;
        float q_ = cq * invM;
        float a = g_kn[c] * rsqrtf(q_ - mean * mean + 1e-5f);
        float bb = b_kn[c] - mean * a;
        float kr = bf2f(kraw[((size_t)b * 512 + c) * NS + 480]);
        float qv = kr * a + bb;
        qa[tid] = qv * a;
        float qb = qv * bb;
        for (int off = 32; off; off >>= 1) qb += __shfl_down(qb, off);
        if (tid == 0) s_qb = qb;
    }
    __syncthreads();

    const int n4 = tid * 4;
    const bool active = n4 < 961;
    float a0 = 0.f, a1 = 0.f, a2 = 0.f, a3 = 0.f;
    if (active) {
        const uint16_t* kp = kraw + ((size_t)b * 512 + h * 64) * NS + n4;
        #pragma unroll 16
        for (int dd = 0; dd < 64; ++dd) {
            uint2 kk = *(const uint2*)(kp + (size_t)dd * NS);
            float q = qa[dd];
            a0 += q * bflo(kk.x);
            a1 += q * bfhi(kk.x);
            a2 += q * bflo(kk.y);
            a3 += q * bfhi(kk.y);
        }
    }
    float lg[4] = {a0, a1, a2, a3};
    float lmax = -1e30f;
    #pragma unroll
    for (int i = 0; i < 4; ++i) {
        lg[i] = (lg[i] + s_qb) * 0.125f;
        if (n4 + i < 961) lmax = fmaxf(lmax, lg[i]);
    }
    for (int off = 32; off; off >>= 1) lmax = fmaxf(lmax, __shfl_xor(lmax, off));
    if ((tid & 63) == 0) red[tid >> 6] = lmax;
    __syncthreads();
    float bmax = fmaxf(fmaxf(red[0], red[1]), fmaxf(red[2], red[3]));

    float lsum = 0.f;
    #pragma unroll
    for (int i = 0; i < 4; ++i) {
        float e = (n4 + i < 961) ? __expf(lg[i] - bmax) : 0.f;
        lg[i] = e;
        lsum += e;
    }
    for (int off = 32; off; off >>= 1) lsum += __shfl_xor(lsum, off);
    if ((tid & 63) == 0) red[4 + (tid >> 6)] = lsum;
    __syncthreads();
    float inv = 1.f / (red[4] + red[5] + red[6] + red[7]);
    if (active) {
        f32x4 v = {lg[0] * inv, lg[1] * inv, lg[2] * inv, lg[3] * inv};
        *(f32x4*)&att[n4] = v;
        *(f32x4*)&attn[(size_t)bh * NS + n4] = v;
    }
    __syncthreads();

    // 31x31 inclusive 2D prefix in LDS (serial: TLP hides it; wave-parallel
    // variant measured r5: 4x more issue work -> slower. Keep serial.)
    if (tid < 31) { float s = 0.f; for (int cc = 0; cc < 31; ++cc) { s += att[tid * 31 + cc]; att[tid * 31 + cc] = s; } }
    __syncthreads();
    if (tid < 31) { float s = 0.f; for (int rr = 0; rr < 31; ++rr) { s += att[rr * 31 + tid]; att[rr * 31 + tid] = s; } }
    __syncthreads();

    if (tid < 75) {
        int i = tid / 5 + 1, t = tid % 5;
        const int m = 15;
        int r0, r1, cc0, cc1;
        switch (t) {
            case 0: r0 = m - i; r1 = m + i + 1; cc0 = m - i; cc1 = m + i + 1; break;
            case 1: r0 = m - i; r1 = m + 1;     cc0 = m - i; cc1 = m + i + 1; break;
            case 2: r0 = m;     r1 = m + i + 1; cc0 = m - i; cc1 = m + i + 1; break;
            case 3: r0 = m - i; r1 = m + i + 1; cc0 = m - i; cc1 = m + 1;     break;
            default:r0 = m - i; r1 = m + i + 1; cc0 = m;     cc1 = m + i + 1; break;
        }
        auto S = [&](int r, int c) -> float { return (r < 0 || c < 0) ? 0.f : att[r * 31 + c]; };
        float box = S(r1 - 1, cc1 - 1) - S(r0 - 1, cc1 - 1) - S(r1 - 1, cc0 - 1) + S(r0 - 1, cc0 - 1);
        float cnt = (float)((r1 - r0) * (cc1 - cc0));
        maw[(size_t)bh * 75 + tid] = box / cnt;
    }
}

// ---------- window box means per (b,c); BN affine from chunk partials ----------
__global__ void k_winbox(const uint16_t* __restrict__ vraw,
                         const float* __restrict__ pp0,
                         const float* __restrict__ g_vn, const float* __restrict__ b_vn,
                         const float* __restrict__ attn, const float* __restrict__ maw,
                         float* __restrict__ y)
{
    __shared__ float xw[NS];
    __shared__ float s_center;
    int bc = blockIdx.x;            // b*512 + c
    int b = bc >> 9, c = bc & 511;
    int h = c >> 6;
    int tid = threadIdx.x;          // 256
    constexpr float invM = 1.f / 61504.f;
    float cs, cq;
    chunk_stats(pp0, c, cs, cq);    // block-uniform broadcast loads
    float mean = cs * invM;
    float q_ = cq * invM;
    float a = g_vn[c] * rsqrtf(q_ - mean * mean + 1e-5f);
    float bb = b_vn[c] - mean * a;
    const uint16_t* vp = vraw + (size_t)bc * NS;
    const float* ap = attn + (size_t)(b * 8 + h) * NS;
    int n4 = tid * 4;
    if (n4 < 961) {
        uint2 kk = *(const uint2*)(vp + n4);
        f32x4 at = *(const f32x4*)(ap + n4);
        f32x4 v;
        v[0] = fmaxf(bflo(kk.x) * a + bb, 0.f) * at[0];
        v[1] = fmaxf(bfhi(kk.x) * a + bb, 0.f) * at[1];
        v[2] = fmaxf(bflo(kk.y) * a + bb, 0.f) * at[2];
        v[3] = fmaxf(bfhi(kk.y) * a + bb, 0.f) * at[3];
        *(f32x4*)&xw[n4] = v;
    }
    __syncthreads();
    if (tid == 0) s_center = xw[480];
    __syncthreads();
    if (tid < 31) { float s = 0.f; for (int cc = 0; cc < 31; ++cc) { s += xw[tid * 31 + cc]; xw[tid * 31 + cc] = s; } }
    __syncthreads();
    if (tid < 31) { float s = 0.f; for (int rr = 0; rr < 31; ++rr) { s += xw[rr * 31 + tid]; xw[rr * 31 + tid] = s; } }
    __syncthreads();
    if (tid < 75) {
        int i = tid / 5 + 1, t = tid % 5;
        const int m = 15;
        int r0, r1, cc0, cc1;
        switch (t) {
            case 0: r0 = m - i; r1 = m + i + 1; cc0 = m - i; cc1 = m + i + 1; break;
            case 1: r0 = m - i; r1 = m + 1;     cc0 = m - i; cc1 = m + i + 1; break;
            case 2: r0 = m;     r1 = m + i + 1; cc0 = m - i; cc1 = m + i + 1; break;
            case 3: r0 = m - i; r1 = m + i + 1; cc0 = m - i; cc1 = m + 1;     break;
            default:r0 = m - i; r1 = m + i + 1; cc0 = m;     cc1 = m + i + 1; break;
        }
        auto S = [&](int r, int cc) -> float { return (r < 0 || cc < 0) ? 0.f : xw[r * 31 + cc]; };
        float box = S(r1 - 1, cc1 - 1) - S(r0 - 1, cc1 - 1) - S(r1 - 1, cc0 - 1) + S(r0 - 1, cc0 - 1);
        float cnt = (float)((r1 - r0) * (cc1 - cc0));
        float mx = box / cnt;
        float ma = maw[(size_t)(b * 8 + h) * 75 + tid];
        y[((size_t)b * 76 + 1 + tid) * 512 + c] = mx / (ma + 1e-16f);
    }
    if (tid == 96) y[((size_t)b * 76) * 512 + c] = s_center;
}

// ---------- row L2-normalize y, build yy = [x0_bf16 | bf16(y/||y||)] ----------
__global__ void k_build_yy(const float* __restrict__ y, const uint16_t* __restrict__ xbt,
                           uint16_t* __restrict__ yy)
{
    __shared__ float red[4];
    int row = blockIdx.x;           // b*76 + r
    int b = row / 76;
    int tid = threadIdx.x;          // 256
    const float* yp = y + (size_t)row * 512;
    float v0 = yp[tid], v1 = yp[tid + 256];
    float ss = v0 * v0 + v1 * v1;
    for (int off = 32; off; off >>= 1) ss += __shfl_xor(ss, off);
    if ((tid & 63) == 0) red[tid >> 6] = ss;
    __syncthreads();
    float tot = red[0] + red[1] + red[2] + red[3];
    float inv = 1.f / fmaxf(sqrtf(tot), 1e-12f);
    uint16_t* op = yy + (size_t)row * 1024;
    const uint16_t* x0p = xbt + ((size_t)b * NS + 480) * 512;
    op[tid]           = x0p[tid];
    op[tid + 256]     = x0p[tid + 256];
    op[512 + tid]       = f2bf(v0 * inv);
    op[512 + tid + 256] = f2bf(v1 * inv);
}

// ---------- final BN + relu (BN affine inline from stats) ----------
__global__ void k_fcout(const float* __restrict__ fcraw,
                        const float* __restrict__ colsum, const float* __restrict__ colsq,
                        const float* __restrict__ g, const float* __restrict__ be,
                        float* __restrict__ out)
{
    size_t idx = (size_t)blockIdx.x * 256 + threadIdx.x;
    if (idx < (size_t)4864 * 512) {
        int j = (int)(idx & 511);
        constexpr float invM = 1.f / 4864.f;
        float mean = colsum[j] * invM;
        float q_ = colsq[j] * invM;
        float a = g[j] * rsqrtf(q_ - mean * mean + 1e-5f);
        float bb = be[j] - mean * a;
        out[idx] = fmaxf(fcraw[idx] * a + bb, 0.f);
    }
}

extern "C" void kernel_launch(void* const* d_in, const int* in_sizes, int n_in,
                              void* d_out, int out_size, void* d_ws, size_t ws_size,
                              hipStream_t stream)
{
    (void)in_sizes; (void)n_in; (void)out_size; (void)ws_size;
    const float* x    = (const float*)d_in[0];
    const float* w_v  = (const float*)d_in[1];
    const float* g_vn = (const float*)d_in[3];
    const float* b_vn = (const float*)d_in[4];
    const float* w_k  = (const float*)d_in[5];
    const float* g_kn = (const float*)d_in[7];
    const float* b_kn = (const float*)d_in[8];
    const float* w_fc = (const float*)d_in[9];
    const float* g_fcn = (const float*)d_in[11];
    const float* b_fcn = (const float*)d_in[12];
    float* out = (float*)d_out;

    char* base = (char*)d_ws;
    size_t off = 0;
    auto alloc = [&](size_t bytes) -> void* {
        void* p = base + off;
        off += (bytes + 255) & ~(size_t)255;
        return p;
    };
    uint16_t* xbt  = (uint16_t*)alloc((size_t)64 * NS * 512 * 2);   // padded rows zeroed
    uint16_t* wvkt = (uint16_t*)alloc((size_t)1024 * 512 * 2);
    uint16_t* wfct = (uint16_t*)alloc((size_t)512 * 1024 * 2);
    uint16_t* vraw = (uint16_t*)alloc((size_t)64 * 512 * NS * 2);
    uint16_t* kraw = (uint16_t*)alloc((size_t)64 * 512 * NS * 2);
    float* stats   = (float*)alloc(3072 * 4);   // fc sum[512] @2048, fc sq[512] @2560
    float* attn    = (float*)alloc((size_t)512 * NS * 4);
    float* maw     = (float*)alloc((size_t)512 * 75 * 4);
    float* y       = (float*)alloc((size_t)64 * 76 * 512 * 4);
    uint16_t* yy   = (uint16_t*)alloc((size_t)4864 * 1024 * 2);
    float* fcraw   = (float*)alloc((size_t)4864 * 512 * 4);
    float* part0   = (float*)alloc((size_t)2 * NMB0 * 1024 * 4);    // deterministic stat partials
    float* part1   = (float*)alloc((size_t)2 * NMB1 * 512 * 4);
    float* pp0     = (float*)alloc((size_t)2 * NCH0 * 1024 * 4);    // stage-A chunk partials

    k_convert<<<12288, 256, 0, stream>>>(x, w_v, w_k, w_fc, xbt, wvkt, wfct);

    // 62*8*8 = 3968 blocks; kernel derives (m,j) with XCD-affine swizzle (496 m-tiles, exact)
    k_gemm<512, 0><<<3968, 256, 0, stream>>>(xbt, wvkt, vraw, kraw, nullptr, part0);
    k_redA<NMB0, 1024><<<dim3(4, NCH0), 256, 0, stream>>>(part0, pp0);

    k_attn<<<512, 256, 0, stream>>>(kraw, pp0, g_kn, b_kn, attn, maw);
    k_winbox<<<64 * 512, 256, 0, stream>>>(vraw, pp0, g_vn, b_vn, attn, maw, y);
    k_build_yy<<<4864, 256, 0, stream>>>(y, xbt, yy);

    k_gemm<1024, 1><<<dim3(4, 38), 256, 0, stream>>>(yy, wfct, nullptr, nullptr, fcraw, part1);
    k_redsmall<NMB1, 512><<<2, 256, 0, stream>>>(part1, stats + 2048, stats + 2560);
    k_fcout<<<9728, 256, 0, stream>>>(fcraw, stats + 2048, stats + 2560, g_fcn, b_fcn, out);
}